// Round 2
// baseline (258.168 us; speedup 1.0000x reference)
//
#include <hip/hip_runtime.h>
#include <stdint.h>

#define BB 2
#define SS 2048
#define DD 1024
#define HH 16
#define DKK 64
#define MT (BB*SS)   // 4096 rows total

#define GSTRIDE 40   // fallback GEMM LDS row stride (elem): conflict-free frags
#define ASTRIDE 72   // attn LDS row stride (elem): conflict-free frags

using short8  = __attribute__((ext_vector_type(8))) short;   // 8 x bf16 bits (4 VGPRs)
using floatx4 = __attribute__((ext_vector_type(4))) float;
using u16x4   = __attribute__((ext_vector_type(4))) unsigned short;
typedef unsigned short u16;

__device__ __forceinline__ u16 f2b(float f) {   // RNE float->bf16
  union { float f; unsigned u; } v; v.f = f;
  return (u16)((v.u + 0x7FFFu + ((v.u >> 16) & 1u)) >> 16);
}
__device__ __forceinline__ void pack16(const float4* p, short8& lo, short8& hi) {
  float4 x0 = p[0], x1 = p[1], x2 = p[2], x3 = p[3];
  lo[0]=(short)f2b(x0.x); lo[1]=(short)f2b(x0.y); lo[2]=(short)f2b(x0.z); lo[3]=(short)f2b(x0.w);
  lo[4]=(short)f2b(x1.x); lo[5]=(short)f2b(x1.y); lo[6]=(short)f2b(x1.z); lo[7]=(short)f2b(x1.w);
  hi[0]=(short)f2b(x2.x); hi[1]=(short)f2b(x2.y); hi[2]=(short)f2b(x2.z); hi[3]=(short)f2b(x2.w);
  hi[4]=(short)f2b(x3.x); hi[5]=(short)f2b(x3.y); hi[6]=(short)f2b(x3.z); hi[7]=(short)f2b(x3.w);
}
// async global->LDS, 16B/lane; lds base wave-uniform, HW scatters lane i at +16*i
__device__ __forceinline__ void gload16(const u16* g, u16* l) {
  __builtin_amdgcn_global_load_lds(
      (const __attribute__((address_space(1))) void*)g,
      (__attribute__((address_space(3))) void*)l, 16, 0, 0);
}

// ---------------------------------------------------------------------------
// One merged cast launch: Q/K/V (2048 blk each) + Wq/Wk/Wv/Wo (512 blk each).
// ---------------------------------------------------------------------------
__global__ __launch_bounds__(256) void cast_all(
    const float* __restrict__ Qin, const float* __restrict__ Kin,
    const float* __restrict__ Vin, const float* __restrict__ Wq,
    const float* __restrict__ Wk,  const float* __restrict__ Wv,
    const float* __restrict__ Wo,
    u16* __restrict__ cQ, u16* __restrict__ cK, u16* __restrict__ cV,
    u16* __restrict__ cWq, u16* __restrict__ cWk, u16* __restrict__ cWv,
    u16* __restrict__ cWo)
{
  const int y = blockIdx.y;
  if (y >= 3 && blockIdx.x >= (DD*DD/8/256)) return;   // weights are 1M elems
  const float* s; u16* d;
  switch (y) {
    case 0: s = Qin; d = cQ;  break;
    case 1: s = Kin; d = cK;  break;
    case 2: s = Vin; d = cV;  break;
    case 3: s = Wq;  d = cWq; break;
    case 4: s = Wk;  d = cWk; break;
    case 5: s = Wv;  d = cWv; break;
    default: s = Wo; d = cWo; break;
  }
  const size_t g = (size_t)blockIdx.x * 256 + threadIdx.x;
  float4 x0 = ((const float4*)s)[g*2], x1 = ((const float4*)s)[g*2+1];
  short8 lo;
  lo[0]=(short)f2b(x0.x); lo[1]=(short)f2b(x0.y); lo[2]=(short)f2b(x0.z); lo[3]=(short)f2b(x0.w);
  lo[4]=(short)f2b(x1.x); lo[5]=(short)f2b(x1.y); lo[6]=(short)f2b(x1.z); lo[7]=(short)f2b(x1.w);
  ((short8*)d)[g] = lo;
}
__global__ __launch_bounds__(256) void cast_w3(
    const float* __restrict__ w0, const float* __restrict__ w1,
    const float* __restrict__ w2, u16* __restrict__ o)
{
  const float* s = (blockIdx.y == 0) ? w0 : (blockIdx.y == 1) ? w1 : w2;
  u16* d = o + (size_t)blockIdx.y * (DD * DD);
  const size_t g = (size_t)blockIdx.x * 256 + threadIdx.x;
  float4 x0 = ((const float4*)s)[g*2], x1 = ((const float4*)s)[g*2+1];
  short8 lo;
  lo[0]=(short)f2b(x0.x); lo[1]=(short)f2b(x0.y); lo[2]=(short)f2b(x0.z); lo[3]=(short)f2b(x0.w);
  lo[4]=(short)f2b(x1.x); lo[5]=(short)f2b(x1.y); lo[6]=(short)f2b(x1.z); lo[7]=(short)f2b(x1.w);
  ((short8*)d)[g] = lo;
}

// ---------------------------------------------------------------------------
// PRIMARY GEMM (BK=64): all-bf16, global_load_lds width-16, 2-barrier K-loop
// with HALF the barriers of BK=32. LDS rows 64 elem (128B); odd rows store
// their two 32-col halves SWAPPED (swizzle applied at the GLOBAL address so
// the linear lane->lds scatter of global_load_lds is preserved). Fragment
// readers XOR the half-select with row parity -> start banks alternate
// 4q / 16+4q across lr parity = conflict-optimal (8 phases / b128 wave read).
// ---------------------------------------------------------------------------
template<bool OUT_F32>
__device__ __forceinline__ void gemm_async(
    const u16* __restrict__ A, const u16* __restrict__ W,
    const float* __restrict__ bias, void* __restrict__ Cv,
    const int K, const int N, const int m0, const int n0, const float scale)
{
  __shared__ __align__(16) u16 sA[128*64];
  __shared__ __align__(16) u16 sB[128*64];

  const int tid  = threadIdx.x;
  const int wave = tid >> 6;
  const int lane = tid & 63;
  const int quad = lane >> 4;
  const int lr   = lane & 15;
  const int wm   = wave >> 1;
  const int wn   = wave & 1;
  const int srow = lane >> 3;                              // 0..7 within chunk
  const int swz  = (((lane & 7) ^ ((srow & 1) << 2)) << 3); // swizzled col (elems)

  floatx4 acc[4][4];
#pragma unroll
  for (int i = 0; i < 4; ++i)
#pragma unroll
    for (int j = 0; j < 4; ++j) acc[i][j] = (floatx4){0.f, 0.f, 0.f, 0.f};

  // chunk = 8 rows x 64 cols = 1KB; wave w stages chunks w, w+4, w+8, w+12
  const u16* pA[4]; const u16* pW[4];
#pragma unroll
  for (int c = 0; c < 4; ++c) {
    const int row = (wave + c*4) * 8 + srow;
    pA[c] = A + (size_t)(m0 + row) * K + swz;
    pW[c] = W + (size_t)(n0 + row) * K + swz;
  }

  const int nk = K >> 6;
  for (int kt = 0; kt < nk; ++kt) {
    const int k0 = kt << 6;
#pragma unroll
    for (int c = 0; c < 4; ++c) {
      gload16(pA[c] + k0, sA + (wave + c*4) * 512);
      gload16(pW[c] + k0, sB + (wave + c*4) * 512);
    }
    __syncthreads();   // drains vmcnt -> staging complete

#pragma unroll
    for (int h2 = 0; h2 < 2; ++h2) {     // two k-halves of the 64-wide tile
      const int csel = (quad << 3) + ((h2 ^ (lr & 1)) << 5);
      short8 af[4], bf[4];
#pragma unroll
      for (int t = 0; t < 4; ++t) {
        af[t] = *(const short8*)(sA + (wm*64 + t*16 + lr)*64 + csel);
        bf[t] = *(const short8*)(sB + (wn*64 + t*16 + lr)*64 + csel);
      }
#pragma unroll
      for (int i = 0; i < 4; ++i)
#pragma unroll
        for (int j = 0; j < 4; ++j)
          acc[i][j] = __builtin_amdgcn_mfma_f32_16x16x32_bf16(af[i], bf[j], acc[i][j], 0, 0, 0);
    }
    __syncthreads();   // reads done before next staging overwrites
  }

  // epilogue: C/D layout col (lane&15) = n, row (quad*4+reg) = m
#pragma unroll
  for (int i = 0; i < 4; ++i) {
    const int mb = m0 + wm*64 + i*16 + quad*4;
#pragma unroll
    for (int j = 0; j < 4; ++j) {
      const int n = n0 + wn*64 + j*16 + lr;
      const float bsv = bias[n];
#pragma unroll
      for (int r = 0; r < 4; ++r) {
        const size_t idx = (size_t)(mb + r) * N + n;
        const float v = (acc[i][j][r] + bsv) * scale;
        if (OUT_F32) ((float*)Cv)[idx] = v;
        else         ((u16*)Cv)[idx]   = f2b(v);
      }
    }
  }
}

__global__ __launch_bounds__(256, 3) void gemm_qkv_async(
    const u16* __restrict__ cQ, const u16* __restrict__ cK, const u16* __restrict__ cV,
    const u16* __restrict__ cWq, const u16* __restrict__ cWk, const u16* __restrict__ cWv,
    const float* __restrict__ bq, const float* __restrict__ bk, const float* __restrict__ bv,
    u16* __restrict__ oQ, u16* __restrict__ oK, u16* __restrict__ oV)
{
  const int wsel = blockIdx.x >> 3;
  const int n0 = (blockIdx.x & 7) * 128;
  const int m0 = blockIdx.y * 128;
  const u16* A; const u16* W; const float* bias; u16* C;
  if (wsel == 0)      { A = cQ; W = cWq; bias = bq; C = oQ; }
  else if (wsel == 1) { A = cK; W = cWk; bias = bk; C = oK; }
  else                { A = cV; W = cWv; bias = bv; C = oV; }
  const float scale = (wsel == 0) ? 0.125f : 1.0f;   // Q pre-scaled by 1/sqrt(dk)
  gemm_async<false>(A, W, bias, C, DD, DD, m0, n0, scale);
}

__global__ __launch_bounds__(256, 3) void gemm_out_async(
    const u16* __restrict__ A, const u16* __restrict__ cWo,
    const float* __restrict__ bias, float* __restrict__ C)
{
  gemm_async<true>(A, cWo, bias, C, DD, DD, blockIdx.y * 128, blockIdx.x * 128, 1.0f);
}

// ---------------------------------------------------------------------------
// FALLBACK GEMM core (round-7 verified): explicit staging, padded LDS.
// ---------------------------------------------------------------------------
template<bool A_BF16, bool W_BF16, bool OUT_F32>
__device__ __forceinline__ void gemm_core(
    const void* __restrict__ A, const void* __restrict__ W,
    const float* __restrict__ bias, void* __restrict__ Cv,
    const int K, const int N, const int m0, const int n0, const float scale)
{
  __shared__ __align__(16) u16 sA[128*GSTRIDE];
  __shared__ __align__(16) u16 sB[128*GSTRIDE];

  const int tid  = threadIdx.x;
  const int wave = tid >> 6;
  const int lane = tid & 63;
  const int quad = lane >> 4;
  const int lr   = lane & 15;
  const int wm   = wave >> 1;
  const int wn   = wave & 1;
  const int srow = tid >> 1;
  const int scol = (tid & 1) * 16;

  floatx4 acc[4][4];
#pragma unroll
  for (int i = 0; i < 4; ++i)
#pragma unroll
    for (int j = 0; j < 4; ++j) acc[i][j] = (floatx4){0.f, 0.f, 0.f, 0.f};

  const size_t offA = (size_t)(m0 + srow) * K + scol;
  const size_t offW = (size_t)(n0 + srow) * K + scol;

  const int nk = K >> 5;
  for (int kt = 0; kt < nk; ++kt) {
    const int k0 = kt << 5;
    short8 a0, a1, b0, b1;
    if (A_BF16) {
      const u16* p = (const u16*)A + offA + k0;
      a0 = *(const short8*)p; a1 = *(const short8*)(p + 8);
    } else {
      pack16((const float4*)((const float*)A + offA + k0), a0, a1);
    }
    if (W_BF16) {
      const u16* p = (const u16*)W + offW + k0;
      b0 = *(const short8*)p; b1 = *(const short8*)(p + 8);
    } else {
      pack16((const float4*)((const float*)W + offW + k0), b0, b1);
    }
    __syncthreads();
    *(short8*)(sA + srow * GSTRIDE + scol)     = a0;
    *(short8*)(sA + srow * GSTRIDE + scol + 8) = a1;
    *(short8*)(sB + srow * GSTRIDE + scol)     = b0;
    *(short8*)(sB + srow * GSTRIDE + scol + 8) = b1;
    __syncthreads();

    short8 af[4], bf[4];
#pragma unroll
    for (int t = 0; t < 4; ++t) {
      af[t] = *(const short8*)(sA + (wm*64 + t*16 + lr)*GSTRIDE + quad*8);
      bf[t] = *(const short8*)(sB + (wn*64 + t*16 + lr)*GSTRIDE + quad*8);
    }
#pragma unroll
    for (int i = 0; i < 4; ++i)
#pragma unroll
      for (int j = 0; j < 4; ++j)
        acc[i][j] = __builtin_amdgcn_mfma_f32_16x16x32_bf16(af[i], bf[j], acc[i][j], 0, 0, 0);
  }

#pragma unroll
  for (int i = 0; i < 4; ++i) {
    const int mb = m0 + wm*64 + i*16 + quad*4;
#pragma unroll
    for (int j = 0; j < 4; ++j) {
      const int n = n0 + wn*64 + j*16 + lr;
      const float bsv = bias[n];
#pragma unroll
      for (int r = 0; r < 4; ++r) {
        const size_t idx = (size_t)(mb + r) * N + n;
        const float v = (acc[i][j][r] + bsv) * scale;
        if (OUT_F32) ((float*)Cv)[idx] = v;
        else         ((u16*)Cv)[idx]   = f2b(v);
      }
    }
  }
}

__global__ __launch_bounds__(256, 2) void gemm_qkv_fb(
    const float* __restrict__ Qin, const float* __restrict__ Kin, const float* __restrict__ Vin,
    const u16* __restrict__ cWq, const u16* __restrict__ cWk, const u16* __restrict__ cWv,
    const float* __restrict__ bq, const float* __restrict__ bk, const float* __restrict__ bv,
    u16* __restrict__ oQ, u16* __restrict__ oK, u16* __restrict__ oV)
{
  const int wsel = blockIdx.x >> 3;
  const int n0 = (blockIdx.x & 7) * 128;
  const int m0 = blockIdx.y * 128;
  const float* A; const u16* W; const float* bias; u16* C;
  if (wsel == 0)      { A = Qin; W = cWq; bias = bq; C = oQ; }
  else if (wsel == 1) { A = Kin; W = cWk; bias = bk; C = oK; }
  else                { A = Vin; W = cWv; bias = bv; C = oV; }
  const float scale = (wsel == 0) ? 0.125f : 1.0f;
  gemm_core<false, true, false>(A, W, bias, C, DD, DD, m0, n0, scale);
}
__global__ __launch_bounds__(256, 2) void gemm_out_fb(
    const u16* __restrict__ A, const float* __restrict__ W,
    const float* __restrict__ bias, float* __restrict__ C)
{
  gemm_core<true, false, true>((const void*)A, (const void*)W, bias, C, DD, DD,
                               blockIdx.y * 128, blockIdx.x * 128, 1.0f);
}

// ---------------------------------------------------------------------------
// V transpose: pV[B,S,D] (head h cols) -> Vt[B,H,dk,S]
// ---------------------------------------------------------------------------
__global__ __launch_bounds__(256) void transpose_v(
    const u16* __restrict__ Vp, u16* __restrict__ Vt)
{
  __shared__ u16 t[64 * 65];
  const int st = blockIdx.x, h = blockIdx.y, b = blockIdx.z;

  const int r  = threadIdx.x >> 2;
  const int c0 = (threadIdx.x & 3) * 16;
  const u16* src = Vp + ((size_t)(b * SS + st * 64 + r)) * DD + h * 64 + c0;
  short8 v0 = *(const short8*)src;
  short8 v1 = *(const short8*)(src + 8);
#pragma unroll
  for (int i = 0; i < 8; ++i) {
    t[r * 65 + c0 + i]     = (u16)v0[i];
    t[r * 65 + c0 + 8 + i] = (u16)v1[i];
  }
  __syncthreads();
  union { u16 a[16]; short8 v[2]; } ob;
#pragma unroll
  for (int i = 0; i < 16; ++i) ob.a[i] = t[(c0 + i) * 65 + r];
  u16* dst = Vt + (((size_t)(b * HH + h)) * DKK + r) * SS + st * 64 + c0;
  *(short8*)dst       = ob.v[0];
  *(short8*)(dst + 8) = ob.v[1];
}

// ---------------------------------------------------------------------------
// Flash attention, q-tile 128: block = 512 threads = 8 waves; each wave owns
// ONE group of 16 q-cols (transposed-S softmax, Q pre-scaled).
//
// R2 revision (occupancy was GRID-limited, not resource-limited):
//  * 512 blocks on 256 CUs = 2 blocks/CU was the cap: 256-thr blocks gave
//    only 8 waves/CU (19% occ). Same grid with 512-thr blocks gives
//    16 waves/CU (4/SIMD) -- double the latency-hiding TLP; per-wave work
//    halves (1 softmax chain instead of 2; cross-wave TLP replaces ILP).
//  * LDS unchanged 36.9 KB (sP: 8 waves x 16 rows = same bytes); 2 blocks
//    x 36.9 KB = 73.7 KB < 160 KB -> still 2 blocks/CU resident.
//  * Q in registers, sP barrier-free (per-wave), XCD-bijective swizzle kept.
// ---------------------------------------------------------------------------
__global__ __launch_bounds__(512, 4) void attn(
    const u16* __restrict__ Qp, const u16* __restrict__ Kp,
    const u16* __restrict__ Vt, u16* __restrict__ O)
{
  __shared__ __align__(16) u16 sK[64 * ASTRIDE];
  __shared__ __align__(16) u16 sV[64 * ASTRIDE];
  __shared__ __align__(16) u16 sP[8][16 * ASTRIDE];   // per wave: 16 q-rows

  const int tid = threadIdx.x, wave = tid >> 6, lane = tid & 63;
  const int quad = lane >> 4, lr = lane & 15;

  // XCD-aware bijective swizzle: flat = (b*16+h)*16+qb over 512 blocks.
  // XCD x (round-robin flat%8) gets work ids x*64..x*64+63 = 4 full (b,h).
  const int flat = (blockIdx.z * 16 + blockIdx.y) * 16 + blockIdx.x;
  const int swzb = (flat & 7) * 64 + (flat >> 3);
  const int qb = swzb & 15;
  const int h  = (swzb >> 4) & 15;
  const int b  = swzb >> 8;
  const size_t vbase = ((size_t)(b * HH + h)) * DKK * SS;

  // Q fragment in registers (this wave's 16 q-cols), loop-invariant
  short8 qf0, qf1;
  {
    const u16* qr = Qp + ((size_t)(b * SS + qb * 128 + wave * 16 + lr)) * DD + h * 64 + quad * 8;
    qf0 = *(const short8*)qr;
    qf1 = *(const short8*)(qr + 32);
  }

  floatx4 accO[4];
  float m_l = -3e38f, l_l = 0.f;
#pragma unroll
  for (int t = 0; t < 4; ++t) accO[t] = (floatx4){0.f, 0.f, 0.f, 0.f};

  // staging addresses: 512 threads, each one short8 of K and of V per iter
  const int sr = tid >> 3, sc = (tid & 7) * 8;
  const u16* kg = Kp + ((size_t)(b * SS + sr)) * DD + h * 64 + sc;
  const u16* vg = Vt + vbase + (size_t)sr * SS + sc;
  u16* dk = sK + sr * ASTRIDE + sc;
  u16* dv = sV + sr * ASTRIDE + sc;

  for (int kt = 0; kt < SS / 64; ++kt) {
    __syncthreads();   // prior iter's sK/sV reads done
    *(short8*)dk = *(const short8*)(kg + (size_t)(kt * 64) * DD);
    *(short8*)dv = *(const short8*)(vg + kt * 64);
    __syncthreads();

    // S^T[k][q] for this wave's 16 q-cols: A = K rows, B = Q rows
    floatx4 st[4];
#pragma unroll
    for (int t = 0; t < 4; ++t) {
      short8 ka0 = *(const short8*)(sK + (t*16 + lr) * ASTRIDE + quad * 8);
      short8 ka1 = *(const short8*)(sK + (t*16 + lr) * ASTRIDE + 32 + quad * 8);
      floatx4 cc = (floatx4){0.f, 0.f, 0.f, 0.f};
      cc = __builtin_amdgcn_mfma_f32_16x16x32_bf16(ka0, qf0, cc, 0, 0, 0);
      cc = __builtin_amdgcn_mfma_f32_16x16x32_bf16(ka1, qf1, cc, 0, 0, 0);
      st[t] = cc;
    }

    float mx = st[0][0];
#pragma unroll
    for (int t = 0; t < 4; ++t)
#pragma unroll
      for (int r = 0; r < 4; ++r) mx = fmaxf(mx, st[t][r]);
    mx = fmaxf(mx, __shfl_xor(mx, 16, 64));
    mx = fmaxf(mx, __shfl_xor(mx, 32, 64));
    const float mn = fmaxf(m_l, mx);
    const float al = __expf(m_l - mn);
    m_l = mn;
    float rs = 0.f;
    u16x4 pk[4];
#pragma unroll
    for (int t = 0; t < 4; ++t)
#pragma unroll
      for (int r = 0; r < 4; ++r) {
        const float p = __expf(st[t][r] - mn);
        rs += p;
        pk[t][r] = f2b(p);
      }
    rs += __shfl_xor(rs, 16, 64);
    rs += __shfl_xor(rs, 32, 64);
    l_l = l_l * al + rs;

    float arow[4];
#pragma unroll
    for (int r = 0; r < 4; ++r) arow[r] = __shfl(al, quad * 4 + r, 64);
#pragma unroll
    for (int t = 0; t < 4; ++t) {
      floatx4 o = accO[t];
      o[0] *= arow[0]; o[1] *= arow[1]; o[2] *= arow[2]; o[3] *= arow[3];
      accO[t] = o;
    }
#pragma unroll
    for (int t = 0; t < 4; ++t)
      *(u16x4*)(sP[wave] + lr * ASTRIDE + t * 16 + quad * 4) = pk[t];
    // no barrier: sP is per-wave; within-wave LDS write->read ordered by lgkmcnt

    // O += P @ V
    short8 p0 = *(const short8*)(sP[wave] + lr * ASTRIDE + quad * 8);
    short8 p1 = *(const short8*)(sP[wave] + lr * ASTRIDE + 32 + quad * 8);
#pragma unroll
    for (int t = 0; t < 4; ++t) {
      short8 v0 = *(const short8*)(sV + (t*16 + lr) * ASTRIDE + quad * 8);
      short8 v1 = *(const short8*)(sV + (t*16 + lr) * ASTRIDE + 32 + quad * 8);
      accO[t] = __builtin_amdgcn_mfma_f32_16x16x32_bf16(p0, v0, accO[t], 0, 0, 0);
      accO[t] = __builtin_amdgcn_mfma_f32_16x16x32_bf16(p1, v1, accO[t], 0, 0, 0);
    }
  }

  {
    float lrow[4];
#pragma unroll
    for (int r = 0; r < 4; ++r) lrow[r] = __shfl(l_l, quad * 4 + r, 64);
#pragma unroll
    for (int t = 0; t < 4; ++t)
#pragma unroll
      for (int r = 0; r < 4; ++r) {
        const int s = qb * 128 + wave * 16 + quad * 4 + r;
        const int d = h * 64 + t * 16 + lr;
        O[((size_t)(b * SS + s)) * DD + d] = f2b(accO[t][r] / lrow[r]);
      }
  }
}

// ---------------------------------------------------------------------------
extern "C" void kernel_launch(void* const* d_in, const int* in_sizes, int n_in,
                              void* d_out, int out_size, void* d_ws, size_t ws_size,
                              hipStream_t stream)
{
  const float* Qin = (const float*)d_in[0];
  const float* Kin = (const float*)d_in[1];
  const float* Vin = (const float*)d_in[2];
  const float* Wq  = (const float*)d_in[3];
  const float* bq  = (const float*)d_in[4];
  const float* Wk  = (const float*)d_in[5];
  const float* bk  = (const float*)d_in[6];
  const float* Wv  = (const float*)d_in[7];
  const float* bv  = (const float*)d_in[8];
  const float* Wo  = (const float*)d_in[9];
  const float* bo  = (const float*)d_in[10];
  float* out = (float*)d_out;

  const size_t TSZ = (size_t)MT * DD;   // 4M elements
  const size_t WSZ = (size_t)DD * DD;   // 1M elements
  dim3 blk(256);

  // d_out scratch for Wq/Wk/Wv bf16 (consumed by gemm_qkv; overwritten at end)
  u16* cWq = (u16*)d_out;
  u16* cWk = cWq + WSZ;
  u16* cWv = cWk + WSZ;

  u16* pQ   = (u16*)d_ws;
  u16* pK   = pQ  + TSZ;
  u16* pV   = pK  + TSZ;
  u16* wsVt = pV  + TSZ;
  u16* wsO  = wsVt + TSZ;

  if (ws_size >= (8*TSZ + WSZ) * sizeof(u16)) {
    u16* cQ  = wsO + TSZ;
    u16* cK  = cQ  + TSZ;
    u16* cV  = cK  + TSZ;
    u16* cWo = cV  + TSZ;
    cast_all<<<dim3(TSZ/8/256, 7), blk, 0, stream>>>(
        Qin, Kin, Vin, Wq, Wk, Wv, Wo, cQ, cK, cV, cWq, cWk, cWv, cWo);
    gemm_qkv_async<<<dim3(24, MT/128), blk, 0, stream>>>(
        cQ, cK, cV, cWq, cWk, cWv, bq, bk, bv, pQ, pK, pV);
    transpose_v<<<dim3(SS/64, HH, BB), blk, 0, stream>>>(pV, wsVt);
    attn<<<dim3(SS/128, HH, BB), dim3(512), 0, stream>>>(pQ, pK, wsVt, wsO);
    gemm_out_async<<<dim3(DD/128, MT/128), blk, 0, stream>>>(wsO, cWo, bo, out);
  } else {
    cast_w3<<<dim3(WSZ/8/256, 3), blk, 0, stream>>>(Wq, Wk, Wv, cWq);
    gemm_qkv_fb<<<dim3(24, MT/128), blk, 0, stream>>>(
        Qin, Kin, Vin, cWq, cWk, cWv, bq, bk, bv, pQ, pK, pV);
    transpose_v<<<dim3(SS/64, HH, BB), blk, 0, stream>>>(pV, wsVt);
    attn<<<dim3(SS/128, HH, BB), dim3(512), 0, stream>>>(pQ, pK, wsVt, wsO);
    gemm_out_fb<<<dim3(DD/128, MT/128), blk, 0, stream>>>(wsO, Wo, bo, out);
  }
}

// Round 3
// 257.195 us; speedup vs baseline: 1.0038x; 1.0038x over previous
//
#include <hip/hip_runtime.h>
#include <stdint.h>

#define BB 2
#define SS 2048
#define DD 1024
#define HH 16
#define DKK 64
#define MT (BB*SS)   // 4096 rows total

#define GSTRIDE 40   // fallback GEMM LDS row stride (elem): conflict-free frags
#define ASTRIDE 72   // attn LDS row stride (elem): conflict-free frags

using short8  = __attribute__((ext_vector_type(8))) short;   // 8 x bf16 bits (4 VGPRs)
using floatx4 = __attribute__((ext_vector_type(4))) float;
using u16x4   = __attribute__((ext_vector_type(4))) unsigned short;
typedef unsigned short u16;

__device__ __forceinline__ u16 f2b(float f) {   // RNE float->bf16
  union { float f; unsigned u; } v; v.f = f;
  return (u16)((v.u + 0x7FFFu + ((v.u >> 16) & 1u)) >> 16);
}
__device__ __forceinline__ void pack16(const float4* p, short8& lo, short8& hi) {
  float4 x0 = p[0], x1 = p[1], x2 = p[2], x3 = p[3];
  lo[0]=(short)f2b(x0.x); lo[1]=(short)f2b(x0.y); lo[2]=(short)f2b(x0.z); lo[3]=(short)f2b(x0.w);
  lo[4]=(short)f2b(x1.x); lo[5]=(short)f2b(x1.y); lo[6]=(short)f2b(x1.z); lo[7]=(short)f2b(x1.w);
  hi[0]=(short)f2b(x2.x); hi[1]=(short)f2b(x2.y); hi[2]=(short)f2b(x2.z); hi[3]=(short)f2b(x2.w);
  hi[4]=(short)f2b(x3.x); hi[5]=(short)f2b(x3.y); hi[6]=(short)f2b(x3.z); hi[7]=(short)f2b(x3.w);
}
// async global->LDS, 16B/lane; lds base wave-uniform, HW scatters lane i at +16*i
__device__ __forceinline__ void gload16(const u16* g, u16* l) {
  __builtin_amdgcn_global_load_lds(
      (const __attribute__((address_space(1))) void*)g,
      (__attribute__((address_space(3))) void*)l, 16, 0, 0);
}

// ---------------------------------------------------------------------------
// One merged cast launch: Q/K/V (2048 blk each) + Wq/Wk/Wv/Wo (512 blk each).
// ---------------------------------------------------------------------------
__global__ __launch_bounds__(256) void cast_all(
    const float* __restrict__ Qin, const float* __restrict__ Kin,
    const float* __restrict__ Vin, const float* __restrict__ Wq,
    const float* __restrict__ Wk,  const float* __restrict__ Wv,
    const float* __restrict__ Wo,
    u16* __restrict__ cQ, u16* __restrict__ cK, u16* __restrict__ cV,
    u16* __restrict__ cWq, u16* __restrict__ cWk, u16* __restrict__ cWv,
    u16* __restrict__ cWo)
{
  const int y = blockIdx.y;
  if (y >= 3 && blockIdx.x >= (DD*DD/8/256)) return;   // weights are 1M elems
  const float* s; u16* d;
  switch (y) {
    case 0: s = Qin; d = cQ;  break;
    case 1: s = Kin; d = cK;  break;
    case 2: s = Vin; d = cV;  break;
    case 3: s = Wq;  d = cWq; break;
    case 4: s = Wk;  d = cWk; break;
    case 5: s = Wv;  d = cWv; break;
    default: s = Wo; d = cWo; break;
  }
  const size_t g = (size_t)blockIdx.x * 256 + threadIdx.x;
  float4 x0 = ((const float4*)s)[g*2], x1 = ((const float4*)s)[g*2+1];
  short8 lo;
  lo[0]=(short)f2b(x0.x); lo[1]=(short)f2b(x0.y); lo[2]=(short)f2b(x0.z); lo[3]=(short)f2b(x0.w);
  lo[4]=(short)f2b(x1.x); lo[5]=(short)f2b(x1.y); lo[6]=(short)f2b(x1.z); lo[7]=(short)f2b(x1.w);
  ((short8*)d)[g] = lo;
}
__global__ __launch_bounds__(256) void cast_w3(
    const float* __restrict__ w0, const float* __restrict__ w1,
    const float* __restrict__ w2, u16* __restrict__ o)
{
  const float* s = (blockIdx.y == 0) ? w0 : (blockIdx.y == 1) ? w1 : w2;
  u16* d = o + (size_t)blockIdx.y * (DD * DD);
  const size_t g = (size_t)blockIdx.x * 256 + threadIdx.x;
  float4 x0 = ((const float4*)s)[g*2], x1 = ((const float4*)s)[g*2+1];
  short8 lo;
  lo[0]=(short)f2b(x0.x); lo[1]=(short)f2b(x0.y); lo[2]=(short)f2b(x0.z); lo[3]=(short)f2b(x0.w);
  lo[4]=(short)f2b(x1.x); lo[5]=(short)f2b(x1.y); lo[6]=(short)f2b(x1.z); lo[7]=(short)f2b(x1.w);
  ((short8*)d)[g] = lo;
}

// ---------------------------------------------------------------------------
// PRIMARY GEMM (BK=64): all-bf16, global_load_lds width-16, 2-barrier K-loop
// with HALF the barriers of BK=32. LDS rows 64 elem (128B); odd rows store
// their two 32-col halves SWAPPED (swizzle applied at the GLOBAL address so
// the linear lane->lds scatter of global_load_lds is preserved). Fragment
// readers XOR the half-select with row parity -> start banks alternate
// 4q / 16+4q across lr parity = conflict-optimal (8 phases / b128 wave read).
// ---------------------------------------------------------------------------
template<bool OUT_F32>
__device__ __forceinline__ void gemm_async(
    const u16* __restrict__ A, const u16* __restrict__ W,
    const float* __restrict__ bias, void* __restrict__ Cv,
    const int K, const int N, const int m0, const int n0, const float scale)
{
  __shared__ __align__(16) u16 sA[128*64];
  __shared__ __align__(16) u16 sB[128*64];

  const int tid  = threadIdx.x;
  const int wave = tid >> 6;
  const int lane = tid & 63;
  const int quad = lane >> 4;
  const int lr   = lane & 15;
  const int wm   = wave >> 1;
  const int wn   = wave & 1;
  const int srow = lane >> 3;                              // 0..7 within chunk
  const int swz  = (((lane & 7) ^ ((srow & 1) << 2)) << 3); // swizzled col (elems)

  floatx4 acc[4][4];
#pragma unroll
  for (int i = 0; i < 4; ++i)
#pragma unroll
    for (int j = 0; j < 4; ++j) acc[i][j] = (floatx4){0.f, 0.f, 0.f, 0.f};

  // chunk = 8 rows x 64 cols = 1KB; wave w stages chunks w, w+4, w+8, w+12
  const u16* pA[4]; const u16* pW[4];
#pragma unroll
  for (int c = 0; c < 4; ++c) {
    const int row = (wave + c*4) * 8 + srow;
    pA[c] = A + (size_t)(m0 + row) * K + swz;
    pW[c] = W + (size_t)(n0 + row) * K + swz;
  }

  const int nk = K >> 6;
  for (int kt = 0; kt < nk; ++kt) {
    const int k0 = kt << 6;
#pragma unroll
    for (int c = 0; c < 4; ++c) {
      gload16(pA[c] + k0, sA + (wave + c*4) * 512);
      gload16(pW[c] + k0, sB + (wave + c*4) * 512);
    }
    __syncthreads();   // drains vmcnt -> staging complete

#pragma unroll
    for (int h2 = 0; h2 < 2; ++h2) {     // two k-halves of the 64-wide tile
      const int csel = (quad << 3) + ((h2 ^ (lr & 1)) << 5);
      short8 af[4], bf[4];
#pragma unroll
      for (int t = 0; t < 4; ++t) {
        af[t] = *(const short8*)(sA + (wm*64 + t*16 + lr)*64 + csel);
        bf[t] = *(const short8*)(sB + (wn*64 + t*16 + lr)*64 + csel);
      }
#pragma unroll
      for (int i = 0; i < 4; ++i)
#pragma unroll
        for (int j = 0; j < 4; ++j)
          acc[i][j] = __builtin_amdgcn_mfma_f32_16x16x32_bf16(af[i], bf[j], acc[i][j], 0, 0, 0);
    }
    __syncthreads();   // reads done before next staging overwrites
  }

  // epilogue: C/D layout col (lane&15) = n, row (quad*4+reg) = m
#pragma unroll
  for (int i = 0; i < 4; ++i) {
    const int mb = m0 + wm*64 + i*16 + quad*4;
#pragma unroll
    for (int j = 0; j < 4; ++j) {
      const int n = n0 + wn*64 + j*16 + lr;
      const float bsv = bias[n];
#pragma unroll
      for (int r = 0; r < 4; ++r) {
        const size_t idx = (size_t)(mb + r) * N + n;
        const float v = (acc[i][j][r] + bsv) * scale;
        if (OUT_F32) ((float*)Cv)[idx] = v;
        else         ((u16*)Cv)[idx]   = f2b(v);
      }
    }
  }
}

__global__ __launch_bounds__(256, 3) void gemm_qkv_async(
    const u16* __restrict__ cQ, const u16* __restrict__ cK, const u16* __restrict__ cV,
    const u16* __restrict__ cWq, const u16* __restrict__ cWk, const u16* __restrict__ cWv,
    const float* __restrict__ bq, const float* __restrict__ bk, const float* __restrict__ bv,
    u16* __restrict__ oQ, u16* __restrict__ oK, u16* __restrict__ oV)
{
  const int wsel = blockIdx.x >> 3;
  const int n0 = (blockIdx.x & 7) * 128;
  const int m0 = blockIdx.y * 128;
  const u16* A; const u16* W; const float* bias; u16* C;
  if (wsel == 0)      { A = cQ; W = cWq; bias = bq; C = oQ; }
  else if (wsel == 1) { A = cK; W = cWk; bias = bk; C = oK; }
  else                { A = cV; W = cWv; bias = bv; C = oV; }
  const float scale = (wsel == 0) ? 0.125f : 1.0f;   // Q pre-scaled by 1/sqrt(dk)
  gemm_async<false>(A, W, bias, C, DD, DD, m0, n0, scale);
}

__global__ __launch_bounds__(256, 3) void gemm_out_async(
    const u16* __restrict__ A, const u16* __restrict__ cWo,
    const float* __restrict__ bias, float* __restrict__ C)
{
  gemm_async<true>(A, cWo, bias, C, DD, DD, blockIdx.y * 128, blockIdx.x * 128, 1.0f);
}

// ---------------------------------------------------------------------------
// FALLBACK GEMM core (round-7 verified): explicit staging, padded LDS.
// ---------------------------------------------------------------------------
template<bool A_BF16, bool W_BF16, bool OUT_F32>
__device__ __forceinline__ void gemm_core(
    const void* __restrict__ A, const void* __restrict__ W,
    const float* __restrict__ bias, void* __restrict__ Cv,
    const int K, const int N, const int m0, const int n0, const float scale)
{
  __shared__ __align__(16) u16 sA[128*GSTRIDE];
  __shared__ __align__(16) u16 sB[128*GSTRIDE];

  const int tid  = threadIdx.x;
  const int wave = tid >> 6;
  const int lane = tid & 63;
  const int quad = lane >> 4;
  const int lr   = lane & 15;
  const int wm   = wave >> 1;
  const int wn   = wave & 1;
  const int srow = tid >> 1;
  const int scol = (tid & 1) * 16;

  floatx4 acc[4][4];
#pragma unroll
  for (int i = 0; i < 4; ++i)
#pragma unroll
    for (int j = 0; j < 4; ++j) acc[i][j] = (floatx4){0.f, 0.f, 0.f, 0.f};

  const size_t offA = (size_t)(m0 + srow) * K + scol;
  const size_t offW = (size_t)(n0 + srow) * K + scol;

  const int nk = K >> 5;
  for (int kt = 0; kt < nk; ++kt) {
    const int k0 = kt << 5;
    short8 a0, a1, b0, b1;
    if (A_BF16) {
      const u16* p = (const u16*)A + offA + k0;
      a0 = *(const short8*)p; a1 = *(const short8*)(p + 8);
    } else {
      pack16((const float4*)((const float*)A + offA + k0), a0, a1);
    }
    if (W_BF16) {
      const u16* p = (const u16*)W + offW + k0;
      b0 = *(const short8*)p; b1 = *(const short8*)(p + 8);
    } else {
      pack16((const float4*)((const float*)W + offW + k0), b0, b1);
    }
    __syncthreads();
    *(short8*)(sA + srow * GSTRIDE + scol)     = a0;
    *(short8*)(sA + srow * GSTRIDE + scol + 8) = a1;
    *(short8*)(sB + srow * GSTRIDE + scol)     = b0;
    *(short8*)(sB + srow * GSTRIDE + scol + 8) = b1;
    __syncthreads();

    short8 af[4], bf[4];
#pragma unroll
    for (int t = 0; t < 4; ++t) {
      af[t] = *(const short8*)(sA + (wm*64 + t*16 + lr)*GSTRIDE + quad*8);
      bf[t] = *(const short8*)(sB + (wn*64 + t*16 + lr)*GSTRIDE + quad*8);
    }
#pragma unroll
    for (int i = 0; i < 4; ++i)
#pragma unroll
      for (int j = 0; j < 4; ++j)
        acc[i][j] = __builtin_amdgcn_mfma_f32_16x16x32_bf16(af[i], bf[j], acc[i][j], 0, 0, 0);
  }

#pragma unroll
  for (int i = 0; i < 4; ++i) {
    const int mb = m0 + wm*64 + i*16 + quad*4;
#pragma unroll
    for (int j = 0; j < 4; ++j) {
      const int n = n0 + wn*64 + j*16 + lr;
      const float bsv = bias[n];
#pragma unroll
      for (int r = 0; r < 4; ++r) {
        const size_t idx = (size_t)(mb + r) * N + n;
        const float v = (acc[i][j][r] + bsv) * scale;
        if (OUT_F32) ((float*)Cv)[idx] = v;
        else         ((u16*)Cv)[idx]   = f2b(v);
      }
    }
  }
}

__global__ __launch_bounds__(256, 2) void gemm_qkv_fb(
    const float* __restrict__ Qin, const float* __restrict__ Kin, const float* __restrict__ Vin,
    const u16* __restrict__ cWq, const u16* __restrict__ cWk, const u16* __restrict__ cWv,
    const float* __restrict__ bq, const float* __restrict__ bk, const float* __restrict__ bv,
    u16* __restrict__ oQ, u16* __restrict__ oK, u16* __restrict__ oV)
{
  const int wsel = blockIdx.x >> 3;
  const int n0 = (blockIdx.x & 7) * 128;
  const int m0 = blockIdx.y * 128;
  const float* A; const u16* W; const float* bias; u16* C;
  if (wsel == 0)      { A = Qin; W = cWq; bias = bq; C = oQ; }
  else if (wsel == 1) { A = Kin; W = cWk; bias = bk; C = oK; }
  else                { A = Vin; W = cWv; bias = bv; C = oV; }
  const float scale = (wsel == 0) ? 0.125f : 1.0f;
  gemm_core<false, true, false>(A, W, bias, C, DD, DD, m0, n0, scale);
}
__global__ __launch_bounds__(256, 2) void gemm_out_fb(
    const u16* __restrict__ A, const float* __restrict__ W,
    const float* __restrict__ bias, float* __restrict__ C)
{
  gemm_core<true, false, true>((const void*)A, (const void*)W, bias, C, DD, DD,
                               blockIdx.y * 128, blockIdx.x * 128, 1.0f);
}

// ---------------------------------------------------------------------------
// V transpose: pV[B,S,D] (head h cols) -> Vt[B,H,dk,S]
// ---------------------------------------------------------------------------
__global__ __launch_bounds__(256) void transpose_v(
    const u16* __restrict__ Vp, u16* __restrict__ Vt)
{
  __shared__ u16 t[64 * 65];
  const int st = blockIdx.x, h = blockIdx.y, b = blockIdx.z;

  const int r  = threadIdx.x >> 2;
  const int c0 = (threadIdx.x & 3) * 16;
  const u16* src = Vp + ((size_t)(b * SS + st * 64 + r)) * DD + h * 64 + c0;
  short8 v0 = *(const short8*)src;
  short8 v1 = *(const short8*)(src + 8);
#pragma unroll
  for (int i = 0; i < 8; ++i) {
    t[r * 65 + c0 + i]     = (u16)v0[i];
    t[r * 65 + c0 + 8 + i] = (u16)v1[i];
  }
  __syncthreads();
  union { u16 a[16]; short8 v[2]; } ob;
#pragma unroll
  for (int i = 0; i < 16; ++i) ob.a[i] = t[(c0 + i) * 65 + r];
  u16* dst = Vt + (((size_t)(b * HH + h)) * DKK + r) * SS + st * 64 + c0;
  *(short8*)dst       = ob.v[0];
  *(short8*)(dst + 8) = ob.v[1];
}

// ---------------------------------------------------------------------------
// Flash attention, q-tile 128: block = 512 threads = 8 waves; each wave owns
// ONE group of 16 q-cols (transposed-S softmax, Q pre-scaled).
//
// R3 revision (R2 showed: occupancy doubled, time flat -> NOT latency-bound;
// bottleneck is the lockstep barrier/stage phase structure):
//  * K/V double-buffered in LDS; staging is SPLIT (T14): global loads for
//    tile kt+2 issue at the top of iter kt (latency hidden under a full
//    iteration of compute); the register->LDS write for tile kt+1 happens
//    before the single barrier. Barriers/iter: 2 -> 1.
//  * LDS 36.9 -> 54 KB; 2 blocks/CU (108 KB) at 512 thr = 16 waves/CU kept.
//  * Arithmetic order unchanged -> bit-identical output vs R2.
//  * Q in registers, sP barrier-free (per-wave), XCD-bijective swizzle kept.
// ---------------------------------------------------------------------------
__global__ __launch_bounds__(512, 4) void attn(
    const u16* __restrict__ Qp, const u16* __restrict__ Kp,
    const u16* __restrict__ Vt, u16* __restrict__ O)
{
  __shared__ __align__(16) u16 sK[2][64 * ASTRIDE];
  __shared__ __align__(16) u16 sV[2][64 * ASTRIDE];
  __shared__ __align__(16) u16 sP[8][16 * ASTRIDE];   // per wave: 16 q-rows

  const int tid = threadIdx.x, wave = tid >> 6, lane = tid & 63;
  const int quad = lane >> 4, lr = lane & 15;

  // XCD-aware bijective swizzle: flat = (b*16+h)*16+qb over 512 blocks.
  // XCD x (round-robin flat%8) gets work ids x*64..x*64+63 = 4 full (b,h).
  const int flat = (blockIdx.z * 16 + blockIdx.y) * 16 + blockIdx.x;
  const int swzb = (flat & 7) * 64 + (flat >> 3);
  const int qb = swzb & 15;
  const int h  = (swzb >> 4) & 15;
  const int b  = swzb >> 8;
  const size_t vbase = ((size_t)(b * HH + h)) * DKK * SS;

  // Q fragment in registers (this wave's 16 q-cols), loop-invariant
  short8 qf0, qf1;
  {
    const u16* qr = Qp + ((size_t)(b * SS + qb * 128 + wave * 16 + lr)) * DD + h * 64 + quad * 8;
    qf0 = *(const short8*)qr;
    qf1 = *(const short8*)(qr + 32);
  }

  floatx4 accO[4];
  float m_l = -3e38f, l_l = 0.f;
#pragma unroll
  for (int t = 0; t < 4; ++t) accO[t] = (floatx4){0.f, 0.f, 0.f, 0.f};

  // staging addresses: 512 threads, each one short8 of K and of V per tile
  const int sr = tid >> 3, sc = (tid & 7) * 8;
  const u16* kp = Kp + ((size_t)(b * SS + sr)) * DD + h * 64 + sc;
  const u16* vp = Vt + vbase + (size_t)sr * SS + sc;
  u16* dkb[2] = { sK[0] + sr * ASTRIDE + sc, sK[1] + sr * ASTRIDE + sc };
  u16* dvb[2] = { sV[0] + sr * ASTRIDE + sc, sV[1] + sr * ASTRIDE + sc };

  // prologue: tile0 -> LDS buf0; tile1 -> regs; one barrier
  short8 rk = *(const short8*)kp;
  short8 rv = *(const short8*)vp;
  *(short8*)dkb[0] = rk;
  *(short8*)dvb[0] = rv;
  kp += (size_t)64 * DD; vp += 64;
  rk = *(const short8*)kp;
  rv = *(const short8*)vp;
  __syncthreads();

  for (int kt = 0; kt < SS / 64; ++kt) {
    const int cur = kt & 1;
    // write tile kt+1 (loaded one iteration ago) into the other buffer
    if (kt < SS / 64 - 1) {
      *(short8*)dkb[cur ^ 1] = rk;
      *(short8*)dvb[cur ^ 1] = rv;
    }
    // issue global loads for tile kt+2 (consumed next iteration)
    if (kt < SS / 64 - 2) {
      kp += (size_t)64 * DD; vp += 64;
      rk = *(const short8*)kp;
      rv = *(const short8*)vp;
    }
    const u16* sKc = sK[cur];
    const u16* sVc = sV[cur];

    // S^T[k][q] for this wave's 16 q-cols: A = K rows, B = Q rows
    floatx4 st[4];
#pragma unroll
    for (int t = 0; t < 4; ++t) {
      short8 ka0 = *(const short8*)(sKc + (t*16 + lr) * ASTRIDE + quad * 8);
      short8 ka1 = *(const short8*)(sKc + (t*16 + lr) * ASTRIDE + 32 + quad * 8);
      floatx4 cc = (floatx4){0.f, 0.f, 0.f, 0.f};
      cc = __builtin_amdgcn_mfma_f32_16x16x32_bf16(ka0, qf0, cc, 0, 0, 0);
      cc = __builtin_amdgcn_mfma_f32_16x16x32_bf16(ka1, qf1, cc, 0, 0, 0);
      st[t] = cc;
    }

    float mx = st[0][0];
#pragma unroll
    for (int t = 0; t < 4; ++t)
#pragma unroll
      for (int r = 0; r < 4; ++r) mx = fmaxf(mx, st[t][r]);
    mx = fmaxf(mx, __shfl_xor(mx, 16, 64));
    mx = fmaxf(mx, __shfl_xor(mx, 32, 64));
    const float mn = fmaxf(m_l, mx);
    const float al = __expf(m_l - mn);
    m_l = mn;
    float rs = 0.f;
    u16x4 pk[4];
#pragma unroll
    for (int t = 0; t < 4; ++t)
#pragma unroll
      for (int r = 0; r < 4; ++r) {
        const float p = __expf(st[t][r] - mn);
        rs += p;
        pk[t][r] = f2b(p);
      }
    rs += __shfl_xor(rs, 16, 64);
    rs += __shfl_xor(rs, 32, 64);
    l_l = l_l * al + rs;

    float arow[4];
#pragma unroll
    for (int r = 0; r < 4; ++r) arow[r] = __shfl(al, quad * 4 + r, 64);
#pragma unroll
    for (int t = 0; t < 4; ++t) {
      floatx4 o = accO[t];
      o[0] *= arow[0]; o[1] *= arow[1]; o[2] *= arow[2]; o[3] *= arow[3];
      accO[t] = o;
    }
#pragma unroll
    for (int t = 0; t < 4; ++t)
      *(u16x4*)(sP[wave] + lr * ASTRIDE + t * 16 + quad * 4) = pk[t];
    // no barrier: sP is per-wave; within-wave LDS write->read ordered by lgkmcnt

    // O += P @ V
    short8 p0 = *(const short8*)(sP[wave] + lr * ASTRIDE + quad * 8);
    short8 p1 = *(const short8*)(sP[wave] + lr * ASTRIDE + 32 + quad * 8);
#pragma unroll
    for (int t = 0; t < 4; ++t) {
      short8 v0 = *(const short8*)(sVc + (t*16 + lr) * ASTRIDE + quad * 8);
      short8 v1 = *(const short8*)(sVc + (t*16 + lr) * ASTRIDE + 32 + quad * 8);
      accO[t] = __builtin_amdgcn_mfma_f32_16x16x32_bf16(p0, v0, accO[t], 0, 0, 0);
      accO[t] = __builtin_amdgcn_mfma_f32_16x16x32_bf16(p1, v1, accO[t], 0, 0, 0);
    }

    __syncthreads();   // single barrier: next-tile writes visible; this-tile reads done
  }

  {
    float lrow[4];
#pragma unroll
    for (int r = 0; r < 4; ++r) lrow[r] = __shfl(l_l, quad * 4 + r, 64);
#pragma unroll
    for (int t = 0; t < 4; ++t)
#pragma unroll
      for (int r = 0; r < 4; ++r) {
        const int s = qb * 128 + wave * 16 + quad * 4 + r;
        const int d = h * 64 + t * 16 + lr;
        O[((size_t)(b * SS + s)) * DD + d] = f2b(accO[t][r] / lrow[r]);
      }
  }
}

// ---------------------------------------------------------------------------
extern "C" void kernel_launch(void* const* d_in, const int* in_sizes, int n_in,
                              void* d_out, int out_size, void* d_ws, size_t ws_size,
                              hipStream_t stream)
{
  const float* Qin = (const float*)d_in[0];
  const float* Kin = (const float*)d_in[1];
  const float* Vin = (const float*)d_in[2];
  const float* Wq  = (const float*)d_in[3];
  const float* bq  = (const float*)d_in[4];
  const float* Wk  = (const float*)d_in[5];
  const float* bk  = (const float*)d_in[6];
  const float* Wv  = (const float*)d_in[7];
  const float* bv  = (const float*)d_in[8];
  const float* Wo  = (const float*)d_in[9];
  const float* bo  = (const float*)d_in[10];
  float* out = (float*)d_out;

  const size_t TSZ = (size_t)MT * DD;   // 4M elements
  const size_t WSZ = (size_t)DD * DD;   // 1M elements
  dim3 blk(256);

  // d_out scratch for Wq/Wk/Wv bf16 (consumed by gemm_qkv; overwritten at end)
  u16* cWq = (u16*)d_out;
  u16* cWk = cWq + WSZ;
  u16* cWv = cWk + WSZ;

  u16* pQ   = (u16*)d_ws;
  u16* pK   = pQ  + TSZ;
  u16* pV   = pK  + TSZ;
  u16* wsVt = pV  + TSZ;
  u16* wsO  = wsVt + TSZ;

  if (ws_size >= (8*TSZ + WSZ) * sizeof(u16)) {
    u16* cQ  = wsO + TSZ;
    u16* cK  = cQ  + TSZ;
    u16* cV  = cK  + TSZ;
    u16* cWo = cV  + TSZ;
    cast_all<<<dim3(TSZ/8/256, 7), blk, 0, stream>>>(
        Qin, Kin, Vin, Wq, Wk, Wv, Wo, cQ, cK, cV, cWq, cWk, cWv, cWo);
    gemm_qkv_async<<<dim3(24, MT/128), blk, 0, stream>>>(
        cQ, cK, cV, cWq, cWk, cWv, bq, bk, bv, pQ, pK, pV);
    transpose_v<<<dim3(SS/64, HH, BB), blk, 0, stream>>>(pV, wsVt);
    attn<<<dim3(SS/128, HH, BB), dim3(512), 0, stream>>>(pQ, pK, wsVt, wsO);
    gemm_out_async<<<dim3(DD/128, MT/128), blk, 0, stream>>>(wsO, cWo, bo, out);
  } else {
    cast_w3<<<dim3(WSZ/8/256, 3), blk, 0, stream>>>(Wq, Wk, Wv, cWq);
    gemm_qkv_fb<<<dim3(24, MT/128), blk, 0, stream>>>(
        Qin, Kin, Vin, cWq, cWk, cWv, bq, bk, bv, pQ, pK, pV);
    transpose_v<<<dim3(SS/64, HH, BB), blk, 0, stream>>>(pV, wsVt);
    attn<<<dim3(SS/128, HH, BB), dim3(512), 0, stream>>>(pQ, pK, wsVt, wsO);
    gemm_out_fb<<<dim3(DD/128, MT/128), blk, 0, stream>>>(wsO, Wo, bo, out);
  }
}

// Round 4
// 251.215 us; speedup vs baseline: 1.0277x; 1.0238x over previous
//
#include <hip/hip_runtime.h>
#include <stdint.h>

#define BB 2
#define SS 2048
#define DD 1024
#define HH 16
#define DKK 64
#define MT (BB*SS)   // 4096 rows total

#define GSTRIDE 40   // fallback GEMM LDS row stride (elem): conflict-free frags

using short8  = __attribute__((ext_vector_type(8))) short;   // 8 x bf16 bits (4 VGPRs)
using floatx4 = __attribute__((ext_vector_type(4))) float;
using u16x4   = __attribute__((ext_vector_type(4))) unsigned short;
typedef unsigned short u16;

__device__ __forceinline__ u16 f2b(float f) {   // RNE float->bf16
  union { float f; unsigned u; } v; v.f = f;
  return (u16)((v.u + 0x7FFFu + ((v.u >> 16) & 1u)) >> 16);
}
__device__ __forceinline__ void pack16(const float4* p, short8& lo, short8& hi) {
  float4 x0 = p[0], x1 = p[1], x2 = p[2], x3 = p[3];
  lo[0]=(short)f2b(x0.x); lo[1]=(short)f2b(x0.y); lo[2]=(short)f2b(x0.z); lo[3]=(short)f2b(x0.w);
  lo[4]=(short)f2b(x1.x); lo[5]=(short)f2b(x1.y); lo[6]=(short)f2b(x1.z); lo[7]=(short)f2b(x1.w);
  hi[0]=(short)f2b(x2.x); hi[1]=(short)f2b(x2.y); hi[2]=(short)f2b(x2.z); hi[3]=(short)f2b(x2.w);
  hi[4]=(short)f2b(x3.x); hi[5]=(short)f2b(x3.y); hi[6]=(short)f2b(x3.z); hi[7]=(short)f2b(x3.w);
}
// async global->LDS, 16B/lane; lds base wave-uniform, HW scatters lane i at +16*i
__device__ __forceinline__ void gload16(const u16* g, u16* l) {
  __builtin_amdgcn_global_load_lds(
      (const __attribute__((address_space(1))) void*)g,
      (__attribute__((address_space(3))) void*)l, 16, 0, 0);
}

// ---------------------------------------------------------------------------
// One merged cast launch: Q/K/V (2048 blk each) + Wq/Wk/Wv/Wo (512 blk each).
// ---------------------------------------------------------------------------
__global__ __launch_bounds__(256) void cast_all(
    const float* __restrict__ Qin, const float* __restrict__ Kin,
    const float* __restrict__ Vin, const float* __restrict__ Wq,
    const float* __restrict__ Wk,  const float* __restrict__ Wv,
    const float* __restrict__ Wo,
    u16* __restrict__ cQ, u16* __restrict__ cK, u16* __restrict__ cV,
    u16* __restrict__ cWq, u16* __restrict__ cWk, u16* __restrict__ cWv,
    u16* __restrict__ cWo)
{
  const int y = blockIdx.y;
  if (y >= 3 && blockIdx.x >= (DD*DD/8/256)) return;   // weights are 1M elems
  const float* s; u16* d;
  switch (y) {
    case 0: s = Qin; d = cQ;  break;
    case 1: s = Kin; d = cK;  break;
    case 2: s = Vin; d = cV;  break;
    case 3: s = Wq;  d = cWq; break;
    case 4: s = Wk;  d = cWk; break;
    case 5: s = Wv;  d = cWv; break;
    default: s = Wo; d = cWo; break;
  }
  const size_t g = (size_t)blockIdx.x * 256 + threadIdx.x;
  float4 x0 = ((const float4*)s)[g*2], x1 = ((const float4*)s)[g*2+1];
  short8 lo;
  lo[0]=(short)f2b(x0.x); lo[1]=(short)f2b(x0.y); lo[2]=(short)f2b(x0.z); lo[3]=(short)f2b(x0.w);
  lo[4]=(short)f2b(x1.x); lo[5]=(short)f2b(x1.y); lo[6]=(short)f2b(x1.z); lo[7]=(short)f2b(x1.w);
  ((short8*)d)[g] = lo;
}
__global__ __launch_bounds__(256) void cast_w3(
    const float* __restrict__ w0, const float* __restrict__ w1,
    const float* __restrict__ w2, u16* __restrict__ o)
{
  const float* s = (blockIdx.y == 0) ? w0 : (blockIdx.y == 1) ? w1 : w2;
  u16* d = o + (size_t)blockIdx.y * (DD * DD);
  const size_t g = (size_t)blockIdx.x * 256 + threadIdx.x;
  float4 x0 = ((const float4*)s)[g*2], x1 = ((const float4*)s)[g*2+1];
  short8 lo;
  lo[0]=(short)f2b(x0.x); lo[1]=(short)f2b(x0.y); lo[2]=(short)f2b(x0.z); lo[3]=(short)f2b(x0.w);
  lo[4]=(short)f2b(x1.x); lo[5]=(short)f2b(x1.y); lo[6]=(short)f2b(x1.z); lo[7]=(short)f2b(x1.w);
  ((short8*)d)[g] = lo;
}

// ---------------------------------------------------------------------------
// PRIMARY GEMM (BK=64): all-bf16, global_load_lds width-16, 2-barrier K-loop.
// ---------------------------------------------------------------------------
template<bool OUT_F32>
__device__ __forceinline__ void gemm_async(
    const u16* __restrict__ A, const u16* __restrict__ W,
    const float* __restrict__ bias, void* __restrict__ Cv,
    const int K, const int N, const int m0, const int n0, const float scale)
{
  __shared__ __align__(16) u16 sA[128*64];
  __shared__ __align__(16) u16 sB[128*64];

  const int tid  = threadIdx.x;
  const int wave = tid >> 6;
  const int lane = tid & 63;
  const int quad = lane >> 4;
  const int lr   = lane & 15;
  const int wm   = wave >> 1;
  const int wn   = wave & 1;
  const int srow = lane >> 3;                              // 0..7 within chunk
  const int swz  = (((lane & 7) ^ ((srow & 1) << 2)) << 3); // swizzled col (elems)

  floatx4 acc[4][4];
#pragma unroll
  for (int i = 0; i < 4; ++i)
#pragma unroll
    for (int j = 0; j < 4; ++j) acc[i][j] = (floatx4){0.f, 0.f, 0.f, 0.f};

  // chunk = 8 rows x 64 cols = 1KB; wave w stages chunks w, w+4, w+8, w+12
  const u16* pA[4]; const u16* pW[4];
#pragma unroll
  for (int c = 0; c < 4; ++c) {
    const int row = (wave + c*4) * 8 + srow;
    pA[c] = A + (size_t)(m0 + row) * K + swz;
    pW[c] = W + (size_t)(n0 + row) * K + swz;
  }

  const int nk = K >> 6;
  for (int kt = 0; kt < nk; ++kt) {
    const int k0 = kt << 6;
#pragma unroll
    for (int c = 0; c < 4; ++c) {
      gload16(pA[c] + k0, sA + (wave + c*4) * 512);
      gload16(pW[c] + k0, sB + (wave + c*4) * 512);
    }
    __syncthreads();   // drains vmcnt -> staging complete

#pragma unroll
    for (int h2 = 0; h2 < 2; ++h2) {     // two k-halves of the 64-wide tile
      const int csel = (quad << 3) + ((h2 ^ (lr & 1)) << 5);
      short8 af[4], bf[4];
#pragma unroll
      for (int t = 0; t < 4; ++t) {
        af[t] = *(const short8*)(sA + (wm*64 + t*16 + lr)*64 + csel);
        bf[t] = *(const short8*)(sB + (wn*64 + t*16 + lr)*64 + csel);
      }
#pragma unroll
      for (int i = 0; i < 4; ++i)
#pragma unroll
        for (int j = 0; j < 4; ++j)
          acc[i][j] = __builtin_amdgcn_mfma_f32_16x16x32_bf16(af[i], bf[j], acc[i][j], 0, 0, 0);
    }
    __syncthreads();   // reads done before next staging overwrites
  }

  // epilogue: C/D layout col (lane&15) = n, row (quad*4+reg) = m
#pragma unroll
  for (int i = 0; i < 4; ++i) {
    const int mb = m0 + wm*64 + i*16 + quad*4;
#pragma unroll
    for (int j = 0; j < 4; ++j) {
      const int n = n0 + wn*64 + j*16 + lr;
      const float bsv = bias[n];
#pragma unroll
      for (int r = 0; r < 4; ++r) {
        const size_t idx = (size_t)(mb + r) * N + n;
        const float v = (acc[i][j][r] + bsv) * scale;
        if (OUT_F32) ((float*)Cv)[idx] = v;
        else         ((u16*)Cv)[idx]   = f2b(v);
      }
    }
  }
}

__global__ __launch_bounds__(256, 3) void gemm_qkv_async(
    const u16* __restrict__ cQ, const u16* __restrict__ cK, const u16* __restrict__ cV,
    const u16* __restrict__ cWq, const u16* __restrict__ cWk, const u16* __restrict__ cWv,
    const float* __restrict__ bq, const float* __restrict__ bk, const float* __restrict__ bv,
    u16* __restrict__ oQ, u16* __restrict__ oK, u16* __restrict__ oV)
{
  const int wsel = blockIdx.x >> 3;
  const int n0 = (blockIdx.x & 7) * 128;
  const int m0 = blockIdx.y * 128;
  const u16* A; const u16* W; const float* bias; u16* C;
  if (wsel == 0)      { A = cQ; W = cWq; bias = bq; C = oQ; }
  else if (wsel == 1) { A = cK; W = cWk; bias = bk; C = oK; }
  else                { A = cV; W = cWv; bias = bv; C = oV; }
  const float scale = (wsel == 0) ? 0.125f : 1.0f;   // Q pre-scaled by 1/sqrt(dk)
  gemm_async<false>(A, W, bias, C, DD, DD, m0, n0, scale);
}

__global__ __launch_bounds__(256, 3) void gemm_out_async(
    const u16* __restrict__ A, const u16* __restrict__ cWo,
    const float* __restrict__ bias, float* __restrict__ C)
{
  gemm_async<true>(A, cWo, bias, C, DD, DD, blockIdx.y * 128, blockIdx.x * 128, 1.0f);
}

// ---------------------------------------------------------------------------
// FALLBACK GEMM core (round-7 verified): explicit staging, padded LDS.
// ---------------------------------------------------------------------------
template<bool A_BF16, bool W_BF16, bool OUT_F32>
__device__ __forceinline__ void gemm_core(
    const void* __restrict__ A, const void* __restrict__ W,
    const float* __restrict__ bias, void* __restrict__ Cv,
    const int K, const int N, const int m0, const int n0, const float scale)
{
  __shared__ __align__(16) u16 sA[128*GSTRIDE];
  __shared__ __align__(16) u16 sB[128*GSTRIDE];

  const int tid  = threadIdx.x;
  const int wave = tid >> 6;
  const int lane = tid & 63;
  const int quad = lane >> 4;
  const int lr   = lane & 15;
  const int wm   = wave >> 1;
  const int wn   = wave & 1;
  const int srow = tid >> 1;
  const int scol = (tid & 1) * 16;

  floatx4 acc[4][4];
#pragma unroll
  for (int i = 0; i < 4; ++i)
#pragma unroll
    for (int j = 0; j < 4; ++j) acc[i][j] = (floatx4){0.f, 0.f, 0.f, 0.f};

  const size_t offA = (size_t)(m0 + srow) * K + scol;
  const size_t offW = (size_t)(n0 + srow) * K + scol;

  const int nk = K >> 5;
  for (int kt = 0; kt < nk; ++kt) {
    const int k0 = kt << 5;
    short8 a0, a1, b0, b1;
    if (A_BF16) {
      const u16* p = (const u16*)A + offA + k0;
      a0 = *(const short8*)p; a1 = *(const short8*)(p + 8);
    } else {
      pack16((const float4*)((const float*)A + offA + k0), a0, a1);
    }
    if (W_BF16) {
      const u16* p = (const u16*)W + offW + k0;
      b0 = *(const short8*)p; b1 = *(const short8*)(p + 8);
    } else {
      pack16((const float4*)((const float*)W + offW + k0), b0, b1);
    }
    __syncthreads();
    *(short8*)(sA + srow * GSTRIDE + scol)     = a0;
    *(short8*)(sA + srow * GSTRIDE + scol + 8) = a1;
    *(short8*)(sB + srow * GSTRIDE + scol)     = b0;
    *(short8*)(sB + srow * GSTRIDE + scol + 8) = b1;
    __syncthreads();

    short8 af[4], bf[4];
#pragma unroll
    for (int t = 0; t < 4; ++t) {
      af[t] = *(const short8*)(sA + (wm*64 + t*16 + lr)*GSTRIDE + quad*8);
      bf[t] = *(const short8*)(sB + (wn*64 + t*16 + lr)*GSTRIDE + quad*8);
    }
#pragma unroll
    for (int i = 0; i < 4; ++i)
#pragma unroll
      for (int j = 0; j < 4; ++j)
        acc[i][j] = __builtin_amdgcn_mfma_f32_16x16x32_bf16(af[i], bf[j], acc[i][j], 0, 0, 0);
  }

#pragma unroll
  for (int i = 0; i < 4; ++i) {
    const int mb = m0 + wm*64 + i*16 + quad*4;
#pragma unroll
    for (int j = 0; j < 4; ++j) {
      const int n = n0 + wn*64 + j*16 + lr;
      const float bsv = bias[n];
#pragma unroll
      for (int r = 0; r < 4; ++r) {
        const size_t idx = (size_t)(mb + r) * N + n;
        const float v = (acc[i][j][r] + bsv) * scale;
        if (OUT_F32) ((float*)Cv)[idx] = v;
        else         ((u16*)Cv)[idx]   = f2b(v);
      }
    }
  }
}

__global__ __launch_bounds__(256, 2) void gemm_qkv_fb(
    const float* __restrict__ Qin, const float* __restrict__ Kin, const float* __restrict__ Vin,
    const u16* __restrict__ cWq, const u16* __restrict__ cWk, const u16* __restrict__ cWv,
    const float* __restrict__ bq, const float* __restrict__ bk, const float* __restrict__ bv,
    u16* __restrict__ oQ, u16* __restrict__ oK, u16* __restrict__ oV)
{
  const int wsel = blockIdx.x >> 3;
  const int n0 = (blockIdx.x & 7) * 128;
  const int m0 = blockIdx.y * 128;
  const float* A; const u16* W; const float* bias; u16* C;
  if (wsel == 0)      { A = Qin; W = cWq; bias = bq; C = oQ; }
  else if (wsel == 1) { A = Kin; W = cWk; bias = bk; C = oK; }
  else                { A = Vin; W = cWv; bias = bv; C = oV; }
  const float scale = (wsel == 0) ? 0.125f : 1.0f;
  gemm_core<false, true, false>(A, W, bias, C, DD, DD, m0, n0, scale);
}
__global__ __launch_bounds__(256, 2) void gemm_out_fb(
    const u16* __restrict__ A, const float* __restrict__ W,
    const float* __restrict__ bias, float* __restrict__ C)
{
  gemm_core<true, false, true>((const void*)A, (const void*)W, bias, C, DD, DD,
                               blockIdx.y * 128, blockIdx.x * 128, 1.0f);
}

// ---------------------------------------------------------------------------
// V transpose: pV[B,S,D] (head h cols) -> Vt[B,H,dk,S]
// ---------------------------------------------------------------------------
__global__ __launch_bounds__(256) void transpose_v(
    const u16* __restrict__ Vp, u16* __restrict__ Vt)
{
  __shared__ u16 t[64 * 65];
  const int st = blockIdx.x, h = blockIdx.y, b = blockIdx.z;

  const int r  = threadIdx.x >> 2;
  const int c0 = (threadIdx.x & 3) * 16;
  const u16* src = Vp + ((size_t)(b * SS + st * 64 + r)) * DD + h * 64 + c0;
  short8 v0 = *(const short8*)src;
  short8 v1 = *(const short8*)(src + 8);
#pragma unroll
  for (int i = 0; i < 8; ++i) {
    t[r * 65 + c0 + i]     = (u16)v0[i];
    t[r * 65 + c0 + 8 + i] = (u16)v1[i];
  }
  __syncthreads();
  union { u16 a[16]; short8 v[2]; } ob;
#pragma unroll
  for (int i = 0; i < 16; ++i) ob.a[i] = t[(c0 + i) * 65 + r];
  u16* dst = Vt + (((size_t)(b * HH + h)) * DKK + r) * SS + st * 64 + c0;
  *(short8*)dst       = ob.v[0];
  *(short8*)(dst + 8) = ob.v[1];
}

// ---------------------------------------------------------------------------
// Flash attention, q-tile 128: block = 256 threads = 4 waves; each wave owns
// TWO groups of 16 q-cols (32 q), sharing the K and V fragments across groups.
//
// R4 revision (LDS pipe was the saturated resource: ~66% LDS-unit occupancy
// + 22% bank-conflict cycles; occupancy/barrier changes were all neutral):
//  * K-frags AND V-frags hoisted and shared by both q-groups -> K/V LDS-read
//    traffic per q-row HALVES vs 1-group-per-wave.
//  * LDS layout: linear 128B rows + XOR swizzle (byte ^= (row&7)<<4), the
//    m214-verified conflict fix, applied to sK/sV/sP write+read sides.
//    Replaces pad-72 (which still left multi-way conflicts: 11.5M cyc).
//  * LDS 55.3 -> 48 KB; 2 blocks/CU; 8 waves/CU (occupancy proven non-binding).
//  * Keeps: reg-Q, 1-barrier dbuf pipeline, XCD swizzle. Adds setprio around
//    MFMA clusters (T5, m191 attn +4-7%).
//  * Per-q-row arithmetic order unchanged -> absmax bit-identical.
// ---------------------------------------------------------------------------
__device__ __forceinline__ int aswz(int row, int cb) {   // byte offset in 128B-row tile
  return (row << 7) + (cb ^ ((row & 7) << 4));
}

__global__ __launch_bounds__(256, 2) void attn(
    const u16* __restrict__ Qp, const u16* __restrict__ Kp,
    const u16* __restrict__ Vt, u16* __restrict__ O)
{
  __shared__ __align__(16) char sK[2][64 * 128];
  __shared__ __align__(16) char sV[2][64 * 128];
  __shared__ __align__(16) char sP[4][32 * 128];

  const int tid = threadIdx.x, wave = tid >> 6, lane = tid & 63;
  const int quad = lane >> 4, lr = lane & 15;

  // XCD-aware bijective swizzle over 512 blocks (512%8==0)
  const int flat = (blockIdx.z * 16 + blockIdx.y) * 16 + blockIdx.x;
  const int swzb = (flat & 7) * 64 + (flat >> 3);
  const int qb = swzb & 15;
  const int h  = (swzb >> 4) & 15;
  const int b  = swzb >> 8;
  const size_t vbase = ((size_t)(b * HH + h)) * DKK * SS;

  // Q fragments in registers: [group][k-half], loop-invariant
  short8 qf[2][2];
#pragma unroll
  for (int g = 0; g < 2; ++g) {
    const u16* qr = Qp + ((size_t)(b * SS + qb * 128 + wave * 32 + g * 16 + lr)) * DD + h * 64 + quad * 8;
    qf[g][0] = *(const short8*)qr;
    qf[g][1] = *(const short8*)(qr + 32);
  }

  floatx4 accO[2][4];
  float m_l[2] = { -3e38f, -3e38f }, l_l[2] = { 0.f, 0.f };
#pragma unroll
  for (int g = 0; g < 2; ++g)
#pragma unroll
    for (int t = 0; t < 4; ++t) accO[g][t] = (floatx4){0.f, 0.f, 0.f, 0.f};

  // staging: 256 threads, each 32B (two short8) of K and of V per tile
  const int sr = tid >> 2;            // 0..63 (row)
  const int ce = (tid & 3) * 16;      // elem col 0..48
  const u16* kp = Kp + ((size_t)(b * SS + sr)) * DD + h * 64 + ce;
  const u16* vp = Vt + vbase + (size_t)sr * SS + ce;
  const int dk0 = aswz(sr, ce * 2), dk1 = aswz(sr, ce * 2 + 16);

  // prologue: tile0 -> LDS buf0; tile1 -> regs; one barrier
  short8 rk0 = *(const short8*)kp,        rk1 = *(const short8*)(kp + 8);
  short8 rv0 = *(const short8*)vp,        rv1 = *(const short8*)(vp + 8);
  *(short8*)(sK[0] + dk0) = rk0;  *(short8*)(sK[0] + dk1) = rk1;
  *(short8*)(sV[0] + dk0) = rv0;  *(short8*)(sV[0] + dk1) = rv1;
  kp += (size_t)64 * DD; vp += 64;
  rk0 = *(const short8*)kp;  rk1 = *(const short8*)(kp + 8);
  rv0 = *(const short8*)vp;  rv1 = *(const short8*)(vp + 8);
  __syncthreads();

  const int nt = SS / 64;
  for (int kt = 0; kt < nt; ++kt) {
    const int cur = kt & 1;
    // write tile kt+1 (loaded one iteration ago) into the other buffer
    if (kt < nt - 1) {
      *(short8*)(sK[cur ^ 1] + dk0) = rk0;  *(short8*)(sK[cur ^ 1] + dk1) = rk1;
      *(short8*)(sV[cur ^ 1] + dk0) = rv0;  *(short8*)(sV[cur ^ 1] + dk1) = rv1;
    }
    // issue global loads for tile kt+2 (consumed next iteration)
    if (kt < nt - 2) {
      kp += (size_t)64 * DD; vp += 64;
      rk0 = *(const short8*)kp;  rk1 = *(const short8*)(kp + 8);
      rv0 = *(const short8*)vp;  rv1 = *(const short8*)(vp + 8);
    }
    const char* sKc = sK[cur];
    const char* sVc = sV[cur];
    char* sPw = sP[wave];

    // K and V fragments: loaded ONCE, shared by both q-groups
    short8 kf[4][2], vf[4][2];
#pragma unroll
    for (int t = 0; t < 4; ++t) {
      const int row = t * 16 + lr;
      kf[t][0] = *(const short8*)(sKc + aswz(row, quad * 16));
      kf[t][1] = *(const short8*)(sKc + aswz(row, 64 + quad * 16));
      vf[t][0] = *(const short8*)(sVc + aswz(row, quad * 16));
      vf[t][1] = *(const short8*)(sVc + aswz(row, 64 + quad * 16));
    }

#pragma unroll
    for (int g = 0; g < 2; ++g) {
      // S^T[k][q] for this group's 16 q-cols: A = K rows, B = Q rows
      floatx4 st[4];
      __builtin_amdgcn_s_setprio(1);
#pragma unroll
      for (int t = 0; t < 4; ++t) {
        floatx4 cc = (floatx4){0.f, 0.f, 0.f, 0.f};
        cc = __builtin_amdgcn_mfma_f32_16x16x32_bf16(kf[t][0], qf[g][0], cc, 0, 0, 0);
        cc = __builtin_amdgcn_mfma_f32_16x16x32_bf16(kf[t][1], qf[g][1], cc, 0, 0, 0);
        st[t] = cc;
      }
      __builtin_amdgcn_s_setprio(0);

      float mx = st[0][0];
#pragma unroll
      for (int t = 0; t < 4; ++t)
#pragma unroll
        for (int r = 0; r < 4; ++r) mx = fmaxf(mx, st[t][r]);
      mx = fmaxf(mx, __shfl_xor(mx, 16, 64));
      mx = fmaxf(mx, __shfl_xor(mx, 32, 64));
      const float mn = fmaxf(m_l[g], mx);
      const float al = __expf(m_l[g] - mn);
      m_l[g] = mn;
      float rs = 0.f;
      u16x4 pk[4];
#pragma unroll
      for (int t = 0; t < 4; ++t)
#pragma unroll
        for (int r = 0; r < 4; ++r) {
          const float p = __expf(st[t][r] - mn);
          rs += p;
          pk[t][r] = f2b(p);
        }
      rs += __shfl_xor(rs, 16, 64);
      rs += __shfl_xor(rs, 32, 64);
      l_l[g] = l_l[g] * al + rs;

      float arow[4];
#pragma unroll
      for (int r = 0; r < 4; ++r) arow[r] = __shfl(al, quad * 4 + r, 64);
#pragma unroll
      for (int t = 0; t < 4; ++t) {
        floatx4 o = accO[g][t];
        o[0] *= arow[0]; o[1] *= arow[1]; o[2] *= arow[2]; o[3] *= arow[3];
        accO[g][t] = o;
      }
#pragma unroll
      for (int t = 0; t < 4; ++t)
        *(u16x4*)(sPw + aswz(g * 16 + lr, t * 32 + quad * 8)) = pk[t];
      // no barrier: sP is per-wave; within-wave LDS write->read ordered by lgkmcnt

      // O += P @ V
      short8 p0 = *(const short8*)(sPw + aswz(g * 16 + lr, quad * 16));
      short8 p1 = *(const short8*)(sPw + aswz(g * 16 + lr, 64 + quad * 16));
      __builtin_amdgcn_s_setprio(1);
#pragma unroll
      for (int t = 0; t < 4; ++t) {
        accO[g][t] = __builtin_amdgcn_mfma_f32_16x16x32_bf16(p0, vf[t][0], accO[g][t], 0, 0, 0);
        accO[g][t] = __builtin_amdgcn_mfma_f32_16x16x32_bf16(p1, vf[t][1], accO[g][t], 0, 0, 0);
      }
      __builtin_amdgcn_s_setprio(0);
    }

    __syncthreads();   // single barrier: next-tile writes visible; this-tile reads done
  }

#pragma unroll
  for (int g = 0; g < 2; ++g) {
    float lrow[4];
#pragma unroll
    for (int r = 0; r < 4; ++r) lrow[r] = __shfl(l_l[g], quad * 4 + r, 64);
#pragma unroll
    for (int t = 0; t < 4; ++t)
#pragma unroll
      for (int r = 0; r < 4; ++r) {
        const int s = qb * 128 + wave * 32 + g * 16 + quad * 4 + r;
        const int d = h * 64 + t * 16 + lr;
        O[((size_t)(b * SS + s)) * DD + d] = f2b(accO[g][t][r] / lrow[r]);
      }
  }
}

// ---------------------------------------------------------------------------
extern "C" void kernel_launch(void* const* d_in, const int* in_sizes, int n_in,
                              void* d_out, int out_size, void* d_ws, size_t ws_size,
                              hipStream_t stream)
{
  const float* Qin = (const float*)d_in[0];
  const float* Kin = (const float*)d_in[1];
  const float* Vin = (const float*)d_in[2];
  const float* Wq  = (const float*)d_in[3];
  const float* bq  = (const float*)d_in[4];
  const float* Wk  = (const float*)d_in[5];
  const float* bk  = (const float*)d_in[6];
  const float* Wv  = (const float*)d_in[7];
  const float* bv  = (const float*)d_in[8];
  const float* Wo  = (const float*)d_in[9];
  const float* bo  = (const float*)d_in[10];
  float* out = (float*)d_out;

  const size_t TSZ = (size_t)MT * DD;   // 4M elements
  const size_t WSZ = (size_t)DD * DD;   // 1M elements
  dim3 blk(256);

  // d_out scratch for Wq/Wk/Wv bf16 (consumed by gemm_qkv; overwritten at end)
  u16* cWq = (u16*)d_out;
  u16* cWk = cWq + WSZ;
  u16* cWv = cWk + WSZ;

  u16* pQ   = (u16*)d_ws;
  u16* pK   = pQ  + TSZ;
  u16* pV   = pK  + TSZ;
  u16* wsVt = pV  + TSZ;
  u16* wsO  = wsVt + TSZ;

  if (ws_size >= (8*TSZ + WSZ) * sizeof(u16)) {
    u16* cQ  = wsO + TSZ;
    u16* cK  = cQ  + TSZ;
    u16* cV  = cK  + TSZ;
    u16* cWo = cV  + TSZ;
    cast_all<<<dim3(TSZ/8/256, 7), blk, 0, stream>>>(
        Qin, Kin, Vin, Wq, Wk, Wv, Wo, cQ, cK, cV, cWq, cWk, cWv, cWo);
    gemm_qkv_async<<<dim3(24, MT/128), blk, 0, stream>>>(
        cQ, cK, cV, cWq, cWk, cWv, bq, bk, bv, pQ, pK, pV);
    transpose_v<<<dim3(SS/64, HH, BB), blk, 0, stream>>>(pV, wsVt);
    attn<<<dim3(SS/128, HH, BB), blk, 0, stream>>>(pQ, pK, wsVt, wsO);
    gemm_out_async<<<dim3(DD/128, MT/128), blk, 0, stream>>>(wsO, cWo, bo, out);
  } else {
    cast_w3<<<dim3(WSZ/8/256, 3), blk, 0, stream>>>(Wq, Wk, Wv, cWq);
    gemm_qkv_fb<<<dim3(24, MT/128), blk, 0, stream>>>(
        Qin, Kin, Vin, cWq, cWk, cWv, bq, bk, bv, pQ, pK, pV);
    transpose_v<<<dim3(SS/64, HH, BB), blk, 0, stream>>>(pV, wsVt);
    attn<<<dim3(SS/128, HH, BB), blk, 0, stream>>>(pQ, pK, wsVt, wsO);
    gemm_out_fb<<<dim3(DD/128, MT/128), blk, 0, stream>>>(wsO, Wo, bo, out);
  }
}

// Round 5
// 237.692 us; speedup vs baseline: 1.0861x; 1.0569x over previous
//
#include <hip/hip_runtime.h>
#include <stdint.h>

#define BB 2
#define SS 2048
#define DD 1024
#define HH 16
#define DKK 64
#define MT (BB*SS)   // 4096 rows total

#define GSTRIDE 40   // fallback GEMM LDS row stride (elem): conflict-free frags

using short8  = __attribute__((ext_vector_type(8))) short;   // 8 x bf16 bits (4 VGPRs)
using floatx4 = __attribute__((ext_vector_type(4))) float;
using u16x4   = __attribute__((ext_vector_type(4))) unsigned short;
typedef unsigned short u16;

__device__ __forceinline__ u16 f2b(float f) {   // RNE float->bf16
  union { float f; unsigned u; } v; v.f = f;
  return (u16)((v.u + 0x7FFFu + ((v.u >> 16) & 1u)) >> 16);
}
__device__ __forceinline__ void pack16(const float4* p, short8& lo, short8& hi) {
  float4 x0 = p[0], x1 = p[1], x2 = p[2], x3 = p[3];
  lo[0]=(short)f2b(x0.x); lo[1]=(short)f2b(x0.y); lo[2]=(short)f2b(x0.z); lo[3]=(short)f2b(x0.w);
  lo[4]=(short)f2b(x1.x); lo[5]=(short)f2b(x1.y); lo[6]=(short)f2b(x1.z); lo[7]=(short)f2b(x1.w);
  hi[0]=(short)f2b(x2.x); hi[1]=(short)f2b(x2.y); hi[2]=(short)f2b(x2.z); hi[3]=(short)f2b(x2.w);
  hi[4]=(short)f2b(x3.x); hi[5]=(short)f2b(x3.y); hi[6]=(short)f2b(x3.z); hi[7]=(short)f2b(x3.w);
}
// async global->LDS, 16B/lane; lds base wave-uniform, HW scatters lane i at +16*i
__device__ __forceinline__ void gload16(const u16* g, u16* l) {
  __builtin_amdgcn_global_load_lds(
      (const __attribute__((address_space(1))) void*)g,
      (__attribute__((address_space(3))) void*)l, 16, 0, 0);
}

// ---------------------------------------------------------------------------
// One merged cast launch: Q/K/V (2048 blk each) + Wq/Wk/Wv/Wo (512 blk each).
// ---------------------------------------------------------------------------
__global__ __launch_bounds__(256) void cast_all(
    const float* __restrict__ Qin, const float* __restrict__ Kin,
    const float* __restrict__ Vin, const float* __restrict__ Wq,
    const float* __restrict__ Wk,  const float* __restrict__ Wv,
    const float* __restrict__ Wo,
    u16* __restrict__ cQ, u16* __restrict__ cK, u16* __restrict__ cV,
    u16* __restrict__ cWq, u16* __restrict__ cWk, u16* __restrict__ cWv,
    u16* __restrict__ cWo)
{
  const int y = blockIdx.y;
  if (y >= 3 && blockIdx.x >= (DD*DD/8/256)) return;   // weights are 1M elems
  const float* s; u16* d;
  switch (y) {
    case 0: s = Qin; d = cQ;  break;
    case 1: s = Kin; d = cK;  break;
    case 2: s = Vin; d = cV;  break;
    case 3: s = Wq;  d = cWq; break;
    case 4: s = Wk;  d = cWk; break;
    case 5: s = Wv;  d = cWv; break;
    default: s = Wo; d = cWo; break;
  }
  const size_t g = (size_t)blockIdx.x * 256 + threadIdx.x;
  float4 x0 = ((const float4*)s)[g*2], x1 = ((const float4*)s)[g*2+1];
  short8 lo;
  lo[0]=(short)f2b(x0.x); lo[1]=(short)f2b(x0.y); lo[2]=(short)f2b(x0.z); lo[3]=(short)f2b(x0.w);
  lo[4]=(short)f2b(x1.x); lo[5]=(short)f2b(x1.y); lo[6]=(short)f2b(x1.z); lo[7]=(short)f2b(x1.w);
  ((short8*)d)[g] = lo;
}
__global__ __launch_bounds__(256) void cast_w3(
    const float* __restrict__ w0, const float* __restrict__ w1,
    const float* __restrict__ w2, u16* __restrict__ o)
{
  const float* s = (blockIdx.y == 0) ? w0 : (blockIdx.y == 1) ? w1 : w2;
  u16* d = o + (size_t)blockIdx.y * (DD * DD);
  const size_t g = (size_t)blockIdx.x * 256 + threadIdx.x;
  float4 x0 = ((const float4*)s)[g*2], x1 = ((const float4*)s)[g*2+1];
  short8 lo;
  lo[0]=(short)f2b(x0.x); lo[1]=(short)f2b(x0.y); lo[2]=(short)f2b(x0.z); lo[3]=(short)f2b(x0.w);
  lo[4]=(short)f2b(x1.x); lo[5]=(short)f2b(x1.y); lo[6]=(short)f2b(x1.z); lo[7]=(short)f2b(x1.w);
  ((short8*)d)[g] = lo;
}

// ---------------------------------------------------------------------------
// PRIMARY GEMM (BK=64): all-bf16, global_load_lds width-16, 2-barrier K-loop.
// ---------------------------------------------------------------------------
template<bool OUT_F32>
__device__ __forceinline__ void gemm_async(
    const u16* __restrict__ A, const u16* __restrict__ W,
    const float* __restrict__ bias, void* __restrict__ Cv,
    const int K, const int N, const int m0, const int n0, const float scale)
{
  __shared__ __align__(16) u16 sA[128*64];
  __shared__ __align__(16) u16 sB[128*64];

  const int tid  = threadIdx.x;
  const int wave = tid >> 6;
  const int lane = tid & 63;
  const int quad = lane >> 4;
  const int lr   = lane & 15;
  const int wm   = wave >> 1;
  const int wn   = wave & 1;
  const int srow = lane >> 3;                              // 0..7 within chunk
  const int swz  = (((lane & 7) ^ ((srow & 1) << 2)) << 3); // swizzled col (elems)

  floatx4 acc[4][4];
#pragma unroll
  for (int i = 0; i < 4; ++i)
#pragma unroll
    for (int j = 0; j < 4; ++j) acc[i][j] = (floatx4){0.f, 0.f, 0.f, 0.f};

  // chunk = 8 rows x 64 cols = 1KB; wave w stages chunks w, w+4, w+8, w+12
  const u16* pA[4]; const u16* pW[4];
#pragma unroll
  for (int c = 0; c < 4; ++c) {
    const int row = (wave + c*4) * 8 + srow;
    pA[c] = A + (size_t)(m0 + row) * K + swz;
    pW[c] = W + (size_t)(n0 + row) * K + swz;
  }

  const int nk = K >> 6;
  for (int kt = 0; kt < nk; ++kt) {
    const int k0 = kt << 6;
#pragma unroll
    for (int c = 0; c < 4; ++c) {
      gload16(pA[c] + k0, sA + (wave + c*4) * 512);
      gload16(pW[c] + k0, sB + (wave + c*4) * 512);
    }
    __syncthreads();   // drains vmcnt -> staging complete

#pragma unroll
    for (int h2 = 0; h2 < 2; ++h2) {     // two k-halves of the 64-wide tile
      const int csel = (quad << 3) + ((h2 ^ (lr & 1)) << 5);
      short8 af[4], bf[4];
#pragma unroll
      for (int t = 0; t < 4; ++t) {
        af[t] = *(const short8*)(sA + (wm*64 + t*16 + lr)*64 + csel);
        bf[t] = *(const short8*)(sB + (wn*64 + t*16 + lr)*64 + csel);
      }
#pragma unroll
      for (int i = 0; i < 4; ++i)
#pragma unroll
        for (int j = 0; j < 4; ++j)
          acc[i][j] = __builtin_amdgcn_mfma_f32_16x16x32_bf16(af[i], bf[j], acc[i][j], 0, 0, 0);
    }
    __syncthreads();   // reads done before next staging overwrites
  }

  // epilogue: C/D layout col (lane&15) = n, row (quad*4+reg) = m
#pragma unroll
  for (int i = 0; i < 4; ++i) {
    const int mb = m0 + wm*64 + i*16 + quad*4;
#pragma unroll
    for (int j = 0; j < 4; ++j) {
      const int n = n0 + wn*64 + j*16 + lr;
      const float bsv = bias[n];
#pragma unroll
      for (int r = 0; r < 4; ++r) {
        const size_t idx = (size_t)(mb + r) * N + n;
        const float v = (acc[i][j][r] + bsv) * scale;
        if (OUT_F32) ((float*)Cv)[idx] = v;
        else         ((u16*)Cv)[idx]   = f2b(v);
      }
    }
  }
}

// ---------------------------------------------------------------------------
// QKV GEMM, 1-D grid 768 with XCD-chunked matrix-major mapping:
//   XCD x = bid&7 owns work j = bid>>3 (0..95): matrix = j>>5, then within a
//   matrix 4 m-panels (x*4 + (j&31)>>3) x 8 n-panels (j&7), n-fastest.
//   Per-XCD hot set = one W (2 MB, L2-resident across the whole matrix pass)
//   + one A-panel (256 KB) -> A fetched once per XCD, W once per matrix.
// ---------------------------------------------------------------------------
__global__ __launch_bounds__(256, 3) void gemm_qkv_async(
    const u16* __restrict__ cQ, const u16* __restrict__ cK, const u16* __restrict__ cV,
    const u16* __restrict__ cWq, const u16* __restrict__ cWk, const u16* __restrict__ cWv,
    const float* __restrict__ bq, const float* __restrict__ bk, const float* __restrict__ bv,
    u16* __restrict__ oQ, u16* __restrict__ oK, u16* __restrict__ oV)
{
  const int bid = blockIdx.x;
  const int xcd = bid & 7;
  const int j   = bid >> 3;          // 0..95
  const int mat = j >> 5;            // 0..2
  const int r   = j & 31;
  const int m0  = ((xcd << 2) + (r >> 3)) * 128;   // 0..31 panels
  const int n0  = (r & 7) * 128;
  const u16* A; const u16* W; const float* bias; u16* C;
  if (mat == 0)      { A = cQ; W = cWq; bias = bq; C = oQ; }
  else if (mat == 1) { A = cK; W = cWk; bias = bk; C = oK; }
  else               { A = cV; W = cWv; bias = bv; C = oV; }
  const float scale = (mat == 0) ? 0.125f : 1.0f;   // Q pre-scaled by 1/sqrt(dk)
  gemm_async<false>(A, W, bias, C, DD, DD, m0, n0, scale);
}

// gemm_out: 1-D grid 256, same XCD-chunked mapping (A-panels XCD-local).
__global__ __launch_bounds__(256, 3) void gemm_out_async(
    const u16* __restrict__ A, const u16* __restrict__ cWo,
    const float* __restrict__ bias, float* __restrict__ C)
{
  const int bid = blockIdx.x;
  const int xcd = bid & 7;
  const int j   = bid >> 3;                       // 0..31
  const int m0  = ((xcd << 2) + (j >> 3)) * 128;
  const int n0  = (j & 7) * 128;
  gemm_async<true>(A, cWo, bias, C, DD, DD, m0, n0, 1.0f);
}

// ---------------------------------------------------------------------------
// FALLBACK GEMM core (round-7 verified): explicit staging, padded LDS.
// ---------------------------------------------------------------------------
template<bool A_BF16, bool W_BF16, bool OUT_F32>
__device__ __forceinline__ void gemm_core(
    const void* __restrict__ A, const void* __restrict__ W,
    const float* __restrict__ bias, void* __restrict__ Cv,
    const int K, const int N, const int m0, const int n0, const float scale)
{
  __shared__ __align__(16) u16 sA[128*GSTRIDE];
  __shared__ __align__(16) u16 sB[128*GSTRIDE];

  const int tid  = threadIdx.x;
  const int wave = tid >> 6;
  const int lane = tid & 63;
  const int quad = lane >> 4;
  const int lr   = lane & 15;
  const int wm   = wave >> 1;
  const int wn   = wave & 1;
  const int srow = tid >> 1;
  const int scol = (tid & 1) * 16;

  floatx4 acc[4][4];
#pragma unroll
  for (int i = 0; i < 4; ++i)
#pragma unroll
    for (int j = 0; j < 4; ++j) acc[i][j] = (floatx4){0.f, 0.f, 0.f, 0.f};

  const size_t offA = (size_t)(m0 + srow) * K + scol;
  const size_t offW = (size_t)(n0 + srow) * K + scol;

  const int nk = K >> 5;
  for (int kt = 0; kt < nk; ++kt) {
    const int k0 = kt << 5;
    short8 a0, a1, b0, b1;
    if (A_BF16) {
      const u16* p = (const u16*)A + offA + k0;
      a0 = *(const short8*)p; a1 = *(const short8*)(p + 8);
    } else {
      pack16((const float4*)((const float*)A + offA + k0), a0, a1);
    }
    if (W_BF16) {
      const u16* p = (const u16*)W + offW + k0;
      b0 = *(const short8*)p; b1 = *(const short8*)(p + 8);
    } else {
      pack16((const float4*)((const float*)W + offW + k0), b0, b1);
    }
    __syncthreads();
    *(short8*)(sA + srow * GSTRIDE + scol)     = a0;
    *(short8*)(sA + srow * GSTRIDE + scol + 8) = a1;
    *(short8*)(sB + srow * GSTRIDE + scol)     = b0;
    *(short8*)(sB + srow * GSTRIDE + scol + 8) = b1;
    __syncthreads();

    short8 af[4], bf[4];
#pragma unroll
    for (int t = 0; t < 4; ++t) {
      af[t] = *(const short8*)(sA + (wm*64 + t*16 + lr)*GSTRIDE + quad*8);
      bf[t] = *(const short8*)(sB + (wn*64 + t*16 + lr)*GSTRIDE + quad*8);
    }
#pragma unroll
    for (int i = 0; i < 4; ++i)
#pragma unroll
      for (int j = 0; j < 4; ++j)
        acc[i][j] = __builtin_amdgcn_mfma_f32_16x16x32_bf16(af[i], bf[j], acc[i][j], 0, 0, 0);
  }

#pragma unroll
  for (int i = 0; i < 4; ++i) {
    const int mb = m0 + wm*64 + i*16 + quad*4;
#pragma unroll
    for (int j = 0; j < 4; ++j) {
      const int n = n0 + wn*64 + j*16 + lr;
      const float bsv = bias[n];
#pragma unroll
      for (int r = 0; r < 4; ++r) {
        const size_t idx = (size_t)(mb + r) * N + n;
        const float v = (acc[i][j][r] + bsv) * scale;
        if (OUT_F32) ((float*)Cv)[idx] = v;
        else         ((u16*)Cv)[idx]   = f2b(v);
      }
    }
  }
}

__global__ __launch_bounds__(256, 2) void gemm_qkv_fb(
    const float* __restrict__ Qin, const float* __restrict__ Kin, const float* __restrict__ Vin,
    const u16* __restrict__ cWq, const u16* __restrict__ cWk, const u16* __restrict__ cWv,
    const float* __restrict__ bq, const float* __restrict__ bk, const float* __restrict__ bv,
    u16* __restrict__ oQ, u16* __restrict__ oK, u16* __restrict__ oV)
{
  const int wsel = blockIdx.x >> 3;
  const int n0 = (blockIdx.x & 7) * 128;
  const int m0 = blockIdx.y * 128;
  const float* A; const u16* W; const float* bias; u16* C;
  if (wsel == 0)      { A = Qin; W = cWq; bias = bq; C = oQ; }
  else if (wsel == 1) { A = Kin; W = cWk; bias = bk; C = oK; }
  else                { A = Vin; W = cWv; bias = bv; C = oV; }
  const float scale = (wsel == 0) ? 0.125f : 1.0f;
  gemm_core<false, true, false>(A, W, bias, C, DD, DD, m0, n0, scale);
}
__global__ __launch_bounds__(256, 2) void gemm_out_fb(
    const u16* __restrict__ A, const float* __restrict__ W,
    const float* __restrict__ bias, float* __restrict__ C)
{
  gemm_core<true, false, true>((const void*)A, (const void*)W, bias, C, DD, DD,
                               blockIdx.y * 128, blockIdx.x * 128, 1.0f);
}

// ---------------------------------------------------------------------------
// V transpose: pV[B,S,D] (head h cols) -> Vt[B,H,dk,S]
// ---------------------------------------------------------------------------
__global__ __launch_bounds__(256) void transpose_v(
    const u16* __restrict__ Vp, u16* __restrict__ Vt)
{
  __shared__ u16 t[64 * 65];
  const int st = blockIdx.x, h = blockIdx.y, b = blockIdx.z;

  const int r  = threadIdx.x >> 2;
  const int c0 = (threadIdx.x & 3) * 16;
  const u16* src = Vp + ((size_t)(b * SS + st * 64 + r)) * DD + h * 64 + c0;
  short8 v0 = *(const short8*)src;
  short8 v1 = *(const short8*)(src + 8);
#pragma unroll
  for (int i = 0; i < 8; ++i) {
    t[r * 65 + c0 + i]     = (u16)v0[i];
    t[r * 65 + c0 + 8 + i] = (u16)v1[i];
  }
  __syncthreads();
  union { u16 a[16]; short8 v[2]; } ob;
#pragma unroll
  for (int i = 0; i < 16; ++i) ob.a[i] = t[(c0 + i) * 65 + r];
  u16* dst = Vt + (((size_t)(b * HH + h)) * DKK + r) * SS + st * 64 + c0;
  *(short8*)dst       = ob.v[0];
  *(short8*)(dst + 8) = ob.v[1];
}

// ---------------------------------------------------------------------------
// Flash attention, q-tile 128: block = 256 threads = 4 waves; each wave owns
// TWO groups of 16 q-cols (32 q), sharing the K and V fragments across groups.
//
// R5 revision: defer-rescale (T13, THR=8, HK-verified): skip the O-rescale
// pass (1 exp + 4 shfl + 16 mul off the serial chain) when the tile max
// didn't outgrow the running max by >8 -- true on ~31/32 iterations.
// When the branch fires the arithmetic is IDENTICAL to the old code; when
// skipped it is exact (al=1), so only P magnitudes change (<= e^8, bf16-safe).
// Keeps: reg-Q, shared K/V frags, XOR-swizzled LDS, 1-barrier dbuf pipeline,
// XCD swizzle, setprio.
// ---------------------------------------------------------------------------
__device__ __forceinline__ int aswz(int row, int cb) {   // byte offset in 128B-row tile
  return (row << 7) + (cb ^ ((row & 7) << 4));
}

__global__ __launch_bounds__(256, 2) void attn(
    const u16* __restrict__ Qp, const u16* __restrict__ Kp,
    const u16* __restrict__ Vt, u16* __restrict__ O)
{
  __shared__ __align__(16) char sK[2][64 * 128];
  __shared__ __align__(16) char sV[2][64 * 128];
  __shared__ __align__(16) char sP[4][32 * 128];

  const int tid = threadIdx.x, wave = tid >> 6, lane = tid & 63;
  const int quad = lane >> 4, lr = lane & 15;

  // XCD-aware bijective swizzle over 512 blocks (512%8==0)
  const int flat = (blockIdx.z * 16 + blockIdx.y) * 16 + blockIdx.x;
  const int swzb = (flat & 7) * 64 + (flat >> 3);
  const int qb = swzb & 15;
  const int h  = (swzb >> 4) & 15;
  const int b  = swzb >> 8;
  const size_t vbase = ((size_t)(b * HH + h)) * DKK * SS;

  // Q fragments in registers: [group][k-half], loop-invariant
  short8 qf[2][2];
#pragma unroll
  for (int g = 0; g < 2; ++g) {
    const u16* qr = Qp + ((size_t)(b * SS + qb * 128 + wave * 32 + g * 16 + lr)) * DD + h * 64 + quad * 8;
    qf[g][0] = *(const short8*)qr;
    qf[g][1] = *(const short8*)(qr + 32);
  }

  floatx4 accO[2][4];
  float m_l[2] = { -3e38f, -3e38f }, l_l[2] = { 0.f, 0.f };
#pragma unroll
  for (int g = 0; g < 2; ++g)
#pragma unroll
    for (int t = 0; t < 4; ++t) accO[g][t] = (floatx4){0.f, 0.f, 0.f, 0.f};

  // staging: 256 threads, each 32B (two short8) of K and of V per tile
  const int sr = tid >> 2;            // 0..63 (row)
  const int ce = (tid & 3) * 16;      // elem col 0..48
  const u16* kp = Kp + ((size_t)(b * SS + sr)) * DD + h * 64 + ce;
  const u16* vp = Vt + vbase + (size_t)sr * SS + ce;
  const int dk0 = aswz(sr, ce * 2), dk1 = aswz(sr, ce * 2 + 16);

  // prologue: tile0 -> LDS buf0; tile1 -> regs; one barrier
  short8 rk0 = *(const short8*)kp,        rk1 = *(const short8*)(kp + 8);
  short8 rv0 = *(const short8*)vp,        rv1 = *(const short8*)(vp + 8);
  *(short8*)(sK[0] + dk0) = rk0;  *(short8*)(sK[0] + dk1) = rk1;
  *(short8*)(sV[0] + dk0) = rv0;  *(short8*)(sV[0] + dk1) = rv1;
  kp += (size_t)64 * DD; vp += 64;
  rk0 = *(const short8*)kp;  rk1 = *(const short8*)(kp + 8);
  rv0 = *(const short8*)vp;  rv1 = *(const short8*)(vp + 8);
  __syncthreads();

  const int nt = SS / 64;
  for (int kt = 0; kt < nt; ++kt) {
    const int cur = kt & 1;
    // write tile kt+1 (loaded one iteration ago) into the other buffer
    if (kt < nt - 1) {
      *(short8*)(sK[cur ^ 1] + dk0) = rk0;  *(short8*)(sK[cur ^ 1] + dk1) = rk1;
      *(short8*)(sV[cur ^ 1] + dk0) = rv0;  *(short8*)(sV[cur ^ 1] + dk1) = rv1;
    }
    // issue global loads for tile kt+2 (consumed next iteration)
    if (kt < nt - 2) {
      kp += (size_t)64 * DD; vp += 64;
      rk0 = *(const short8*)kp;  rk1 = *(const short8*)(kp + 8);
      rv0 = *(const short8*)vp;  rv1 = *(const short8*)(vp + 8);
    }
    const char* sKc = sK[cur];
    const char* sVc = sV[cur];
    char* sPw = sP[wave];

    // K and V fragments: loaded ONCE, shared by both q-groups
    short8 kf[4][2], vf[4][2];
#pragma unroll
    for (int t = 0; t < 4; ++t) {
      const int row = t * 16 + lr;
      kf[t][0] = *(const short8*)(sKc + aswz(row, quad * 16));
      kf[t][1] = *(const short8*)(sKc + aswz(row, 64 + quad * 16));
      vf[t][0] = *(const short8*)(sVc + aswz(row, quad * 16));
      vf[t][1] = *(const short8*)(sVc + aswz(row, 64 + quad * 16));
    }

#pragma unroll
    for (int g = 0; g < 2; ++g) {
      // S^T[k][q] for this group's 16 q-cols: A = K rows, B = Q rows
      floatx4 st[4];
      __builtin_amdgcn_s_setprio(1);
#pragma unroll
      for (int t = 0; t < 4; ++t) {
        floatx4 cc = (floatx4){0.f, 0.f, 0.f, 0.f};
        cc = __builtin_amdgcn_mfma_f32_16x16x32_bf16(kf[t][0], qf[g][0], cc, 0, 0, 0);
        cc = __builtin_amdgcn_mfma_f32_16x16x32_bf16(kf[t][1], qf[g][1], cc, 0, 0, 0);
        st[t] = cc;
      }
      __builtin_amdgcn_s_setprio(0);

      float mx = st[0][0];
#pragma unroll
      for (int t = 0; t < 4; ++t)
#pragma unroll
        for (int r = 0; r < 4; ++r) mx = fmaxf(mx, st[t][r]);
      mx = fmaxf(mx, __shfl_xor(mx, 16, 64));
      mx = fmaxf(mx, __shfl_xor(mx, 32, 64));

      // defer-rescale (T13): only rescale when the max grew by > 8
      if (!__all(mx - m_l[g] <= 8.f)) {
        const float mn = fmaxf(m_l[g], mx);
        const float al = __expf(m_l[g] - mn);
        m_l[g] = mn;
        l_l[g] *= al;
        float arow[4];
#pragma unroll
        for (int r = 0; r < 4; ++r) arow[r] = __shfl(al, quad * 4 + r, 64);
#pragma unroll
        for (int t = 0; t < 4; ++t) {
          floatx4 o = accO[g][t];
          o[0] *= arow[0]; o[1] *= arow[1]; o[2] *= arow[2]; o[3] *= arow[3];
          accO[g][t] = o;
        }
      }
      const float mn = m_l[g];

      float rs = 0.f;
      u16x4 pk[4];
#pragma unroll
      for (int t = 0; t < 4; ++t)
#pragma unroll
        for (int r = 0; r < 4; ++r) {
          const float p = __expf(st[t][r] - mn);
          rs += p;
          pk[t][r] = f2b(p);
        }
      rs += __shfl_xor(rs, 16, 64);
      rs += __shfl_xor(rs, 32, 64);
      l_l[g] += rs;

#pragma unroll
      for (int t = 0; t < 4; ++t)
        *(u16x4*)(sPw + aswz(g * 16 + lr, t * 32 + quad * 8)) = pk[t];
      // no barrier: sP is per-wave; within-wave LDS write->read ordered by lgkmcnt

      // O += P @ V
      short8 p0 = *(const short8*)(sPw + aswz(g * 16 + lr, quad * 16));
      short8 p1 = *(const short8*)(sPw + aswz(g * 16 + lr, 64 + quad * 16));
      __builtin_amdgcn_s_setprio(1);
#pragma unroll
      for (int t = 0; t < 4; ++t) {
        accO[g][t] = __builtin_amdgcn_mfma_f32_16x16x32_bf16(p0, vf[t][0], accO[g][t], 0, 0, 0);
        accO[g][t] = __builtin_amdgcn_mfma_f32_16x16x32_bf16(p1, vf[t][1], accO[g][t], 0, 0, 0);
      }
      __builtin_amdgcn_s_setprio(0);
    }

    __syncthreads();   // single barrier: next-tile writes visible; this-tile reads done
  }

#pragma unroll
  for (int g = 0; g < 2; ++g) {
    float lrow[4];
#pragma unroll
    for (int r = 0; r < 4; ++r) lrow[r] = __shfl(l_l[g], quad * 4 + r, 64);
#pragma unroll
    for (int t = 0; t < 4; ++t)
#pragma unroll
      for (int r = 0; r < 4; ++r) {
        const int s = qb * 128 + wave * 32 + g * 16 + quad * 4 + r;
        const int d = h * 64 + t * 16 + lr;
        O[((size_t)(b * SS + s)) * DD + d] = f2b(accO[g][t][r] / lrow[r]);
      }
  }
}

// ---------------------------------------------------------------------------
extern "C" void kernel_launch(void* const* d_in, const int* in_sizes, int n_in,
                              void* d_out, int out_size, void* d_ws, size_t ws_size,
                              hipStream_t stream)
{
  const float* Qin = (const float*)d_in[0];
  const float* Kin = (const float*)d_in[1];
  const float* Vin = (const float*)d_in[2];
  const float* Wq  = (const float*)d_in[3];
  const float* bq  = (const float*)d_in[4];
  const float* Wk  = (const float*)d_in[5];
  const float* bk  = (const float*)d_in[6];
  const float* Wv  = (const float*)d_in[7];
  const float* bv  = (const float*)d_in[8];
  const float* Wo  = (const float*)d_in[9];
  const float* bo  = (const float*)d_in[10];
  float* out = (float*)d_out;

  const size_t TSZ = (size_t)MT * DD;   // 4M elements
  const size_t WSZ = (size_t)DD * DD;   // 1M elements
  dim3 blk(256);

  // d_out scratch for Wq/Wk/Wv bf16 (consumed by gemm_qkv; overwritten at end)
  u16* cWq = (u16*)d_out;
  u16* cWk = cWq + WSZ;
  u16* cWv = cWk + WSZ;

  u16* pQ   = (u16*)d_ws;
  u16* pK   = pQ  + TSZ;
  u16* pV   = pK  + TSZ;
  u16* wsVt = pV  + TSZ;
  u16* wsO  = wsVt + TSZ;

  if (ws_size >= (8*TSZ + WSZ) * sizeof(u16)) {
    u16* cQ  = wsO + TSZ;
    u16* cK  = cQ  + TSZ;
    u16* cV  = cK  + TSZ;
    u16* cWo = cV  + TSZ;
    cast_all<<<dim3(TSZ/8/256, 7), blk, 0, stream>>>(
        Qin, Kin, Vin, Wq, Wk, Wv, Wo, cQ, cK, cV, cWq, cWk, cWv, cWo);
    gemm_qkv_async<<<dim3(768), blk, 0, stream>>>(
        cQ, cK, cV, cWq, cWk, cWv, bq, bk, bv, pQ, pK, pV);
    transpose_v<<<dim3(SS/64, HH, BB), blk, 0, stream>>>(pV, wsVt);
    attn<<<dim3(SS/128, HH, BB), blk, 0, stream>>>(pQ, pK, wsVt, wsO);
    gemm_out_async<<<dim3(256), blk, 0, stream>>>(wsO, cWo, bo, out);
  } else {
    cast_w3<<<dim3(WSZ/8/256, 3), blk, 0, stream>>>(Wq, Wk, Wv, cWq);
    gemm_qkv_fb<<<dim3(24, MT/128), blk, 0, stream>>>(
        Qin, Kin, Vin, cWq, cWk, cWv, bq, bk, bv, pQ, pK, pV);
    transpose_v<<<dim3(SS/64, HH, BB), blk, 0, stream>>>(pV, wsVt);
    attn<<<dim3(SS/128, HH, BB), blk, 0, stream>>>(pQ, pK, wsVt, wsO);
    gemm_out_fb<<<dim3(DD/128, MT/128), blk, 0, stream>>>(wsO, Wo, bo, out);
  }
}

// Round 7
// 230.402 us; speedup vs baseline: 1.1205x; 1.0316x over previous
//
#include <hip/hip_runtime.h>
#include <stdint.h>

#define BB 2
#define SS 2048
#define DD 1024
#define HH 16
#define DKK 64
#define MT (BB*SS)   // 4096 rows total

#define GSTRIDE 40   // fallback GEMM LDS row stride (elem): conflict-free frags

// Q pre-scale: 1/sqrt(dk) * log2(e)  -> softmax uses single-instruction exp2
#define QSCALE 0.18033688011112042f

using short8  = __attribute__((ext_vector_type(8))) short;   // 8 x bf16 bits (4 VGPRs)
using floatx4 = __attribute__((ext_vector_type(4))) float;
using u16x4   = __attribute__((ext_vector_type(4))) unsigned short;
typedef unsigned short u16;

__device__ __forceinline__ float ex2(float x) { return __builtin_amdgcn_exp2f(x); }

__device__ __forceinline__ u16 f2b(float f) {   // RNE float->bf16
  union { float f; unsigned u; } v; v.f = f;
  return (u16)((v.u + 0x7FFFu + ((v.u >> 16) & 1u)) >> 16);
}
// HW packed RNE f32x2 -> bf16x2 (gfx950); bit-identical to f2b for normals
__device__ __forceinline__ unsigned cvt_pk_bf16(float lo, float hi) {
  unsigned r;
  asm("v_cvt_pk_bf16_f32 %0, %1, %2" : "=v"(r) : "v"(lo), "v"(hi));
  return r;
}
__device__ __forceinline__ void pack16(const float4* p, short8& lo, short8& hi) {
  float4 x0 = p[0], x1 = p[1], x2 = p[2], x3 = p[3];
  lo[0]=(short)f2b(x0.x); lo[1]=(short)f2b(x0.y); lo[2]=(short)f2b(x0.z); lo[3]=(short)f2b(x0.w);
  lo[4]=(short)f2b(x1.x); lo[5]=(short)f2b(x1.y); lo[6]=(short)f2b(x1.z); lo[7]=(short)f2b(x1.w);
  hi[0]=(short)f2b(x2.x); hi[1]=(short)f2b(x2.y); hi[2]=(short)f2b(x2.z); hi[3]=(short)f2b(x2.w);
  hi[4]=(short)f2b(x3.x); hi[5]=(short)f2b(x3.y); hi[6]=(short)f2b(x3.z); hi[7]=(short)f2b(x3.w);
}
// async global->LDS, 16B/lane; lds base wave-uniform, HW scatters lane i at +16*i
__device__ __forceinline__ void gload16(const u16* g, u16* l) {
  __builtin_amdgcn_global_load_lds(
      (const __attribute__((address_space(1))) void*)g,
      (__attribute__((address_space(3))) void*)l, 16, 0, 0);
}

// ---------------------------------------------------------------------------
// One merged cast launch: Q/K/V (2048 blk each) + Wq/Wk/Wv/Wo (512 blk each).
// ---------------------------------------------------------------------------
__global__ __launch_bounds__(256) void cast_all(
    const float* __restrict__ Qin, const float* __restrict__ Kin,
    const float* __restrict__ Vin, const float* __restrict__ Wq,
    const float* __restrict__ Wk,  const float* __restrict__ Wv,
    const float* __restrict__ Wo,
    u16* __restrict__ cQ, u16* __restrict__ cK, u16* __restrict__ cV,
    u16* __restrict__ cWq, u16* __restrict__ cWk, u16* __restrict__ cWv,
    u16* __restrict__ cWo)
{
  const int y = blockIdx.y;
  if (y >= 3 && blockIdx.x >= (DD*DD/8/256)) return;   // weights are 1M elems
  const float* s; u16* d;
  switch (y) {
    case 0: s = Qin; d = cQ;  break;
    case 1: s = Kin; d = cK;  break;
    case 2: s = Vin; d = cV;  break;
    case 3: s = Wq;  d = cWq; break;
    case 4: s = Wk;  d = cWk; break;
    case 5: s = Wv;  d = cWv; break;
    default: s = Wo; d = cWo; break;
  }
  const size_t g = (size_t)blockIdx.x * 256 + threadIdx.x;
  float4 x0 = ((const float4*)s)[g*2], x1 = ((const float4*)s)[g*2+1];
  short8 lo;
  lo[0]=(short)f2b(x0.x); lo[1]=(short)f2b(x0.y); lo[2]=(short)f2b(x0.z); lo[3]=(short)f2b(x0.w);
  lo[4]=(short)f2b(x1.x); lo[5]=(short)f2b(x1.y); lo[6]=(short)f2b(x1.z); lo[7]=(short)f2b(x1.w);
  ((short8*)d)[g] = lo;
}
__global__ __launch_bounds__(256) void cast_w3(
    const float* __restrict__ w0, const float* __restrict__ w1,
    const float* __restrict__ w2, u16* __restrict__ o)
{
  const float* s = (blockIdx.y == 0) ? w0 : (blockIdx.y == 1) ? w1 : w2;
  u16* d = o + (size_t)blockIdx.y * (DD * DD);
  const size_t g = (size_t)blockIdx.x * 256 + threadIdx.x;
  float4 x0 = ((const float4*)s)[g*2], x1 = ((const float4*)s)[g*2+1];
  short8 lo;
  lo[0]=(short)f2b(x0.x); lo[1]=(short)f2b(x0.y); lo[2]=(short)f2b(x0.z); lo[3]=(short)f2b(x0.w);
  lo[4]=(short)f2b(x1.x); lo[5]=(short)f2b(x1.y); lo[6]=(short)f2b(x1.z); lo[7]=(short)f2b(x1.w);
  ((short8*)d)[g] = lo;
}

// ---------------------------------------------------------------------------
// PRIMARY GEMM (BK=64): all-bf16, global_load_lds width-16, 2-barrier K-loop.
// ---------------------------------------------------------------------------
template<bool OUT_F32>
__device__ __forceinline__ void gemm_async(
    const u16* __restrict__ A, const u16* __restrict__ W,
    const float* __restrict__ bias, void* __restrict__ Cv,
    const int K, const int N, const int m0, const int n0, const float scale)
{
  __shared__ __align__(16) u16 sA[128*64];
  __shared__ __align__(16) u16 sB[128*64];

  const int tid  = threadIdx.x;
  const int wave = tid >> 6;
  const int lane = tid & 63;
  const int quad = lane >> 4;
  const int lr   = lane & 15;
  const int wm   = wave >> 1;
  const int wn   = wave & 1;
  const int srow = lane >> 3;                              // 0..7 within chunk
  const int swz  = (((lane & 7) ^ ((srow & 1) << 2)) << 3); // swizzled col (elems)

  floatx4 acc[4][4];
#pragma unroll
  for (int i = 0; i < 4; ++i)
#pragma unroll
    for (int j = 0; j < 4; ++j) acc[i][j] = (floatx4){0.f, 0.f, 0.f, 0.f};

  // chunk = 8 rows x 64 cols = 1KB; wave w stages chunks w, w+4, w+8, w+12
  const u16* pA[4]; const u16* pW[4];
#pragma unroll
  for (int c = 0; c < 4; ++c) {
    const int row = (wave + c*4) * 8 + srow;
    pA[c] = A + (size_t)(m0 + row) * K + swz;
    pW[c] = W + (size_t)(n0 + row) * K + swz;
  }

  const int nk = K >> 6;
  for (int kt = 0; kt < nk; ++kt) {
    const int k0 = kt << 6;
#pragma unroll
    for (int c = 0; c < 4; ++c) {
      gload16(pA[c] + k0, sA + (wave + c*4) * 512);
      gload16(pW[c] + k0, sB + (wave + c*4) * 512);
    }
    __syncthreads();   // drains vmcnt -> staging complete

#pragma unroll
    for (int h2 = 0; h2 < 2; ++h2) {     // two k-halves of the 64-wide tile
      const int csel = (quad << 3) + ((h2 ^ (lr & 1)) << 5);
      short8 af[4], bf[4];
#pragma unroll
      for (int t = 0; t < 4; ++t) {
        af[t] = *(const short8*)(sA + (wm*64 + t*16 + lr)*64 + csel);
        bf[t] = *(const short8*)(sB + (wn*64 + t*16 + lr)*64 + csel);
      }
#pragma unroll
      for (int i = 0; i < 4; ++i)
#pragma unroll
        for (int j = 0; j < 4; ++j)
          acc[i][j] = __builtin_amdgcn_mfma_f32_16x16x32_bf16(af[i], bf[j], acc[i][j], 0, 0, 0);
    }
    __syncthreads();   // reads done before next staging overwrites
  }

  // epilogue: C/D layout col (lane&15) = n, row (quad*4+reg) = m
#pragma unroll
  for (int i = 0; i < 4; ++i) {
    const int mb = m0 + wm*64 + i*16 + quad*4;
#pragma unroll
    for (int j = 0; j < 4; ++j) {
      const int n = n0 + wn*64 + j*16 + lr;
      const float bsv = bias[n];
#pragma unroll
      for (int r = 0; r < 4; ++r) {
        const size_t idx = (size_t)(mb + r) * N + n;
        const float v = (acc[i][j][r] + bsv) * scale;
        if (OUT_F32) ((float*)Cv)[idx] = v;
        else         ((u16*)Cv)[idx]   = f2b(v);
      }
    }
  }
}

// ---------------------------------------------------------------------------
// QKV GEMM, 1-D grid 768 with XCD-chunked matrix-major mapping.
// ---------------------------------------------------------------------------
__global__ __launch_bounds__(256, 3) void gemm_qkv_async(
    const u16* __restrict__ cQ, const u16* __restrict__ cK, const u16* __restrict__ cV,
    const u16* __restrict__ cWq, const u16* __restrict__ cWk, const u16* __restrict__ cWv,
    const float* __restrict__ bq, const float* __restrict__ bk, const float* __restrict__ bv,
    u16* __restrict__ oQ, u16* __restrict__ oK, u16* __restrict__ oV)
{
  const int bid = blockIdx.x;
  const int xcd = bid & 7;
  const int j   = bid >> 3;          // 0..95
  const int mat = j >> 5;            // 0..2
  const int r   = j & 31;
  const int m0  = ((xcd << 2) + (r >> 3)) * 128;   // 0..31 panels
  const int n0  = (r & 7) * 128;
  const u16* A; const u16* W; const float* bias; u16* C;
  if (mat == 0)      { A = cQ; W = cWq; bias = bq; C = oQ; }
  else if (mat == 1) { A = cK; W = cWk; bias = bk; C = oK; }
  else               { A = cV; W = cWv; bias = bv; C = oV; }
  const float scale = (mat == 0) ? QSCALE : 1.0f;   // Q pre-scaled by log2e/sqrt(dk)
  gemm_async<false>(A, W, bias, C, DD, DD, m0, n0, scale);
}

// gemm_out: 1-D grid 256, same XCD-chunked mapping (A-panels XCD-local).
__global__ __launch_bounds__(256, 3) void gemm_out_async(
    const u16* __restrict__ A, const u16* __restrict__ cWo,
    const float* __restrict__ bias, float* __restrict__ C)
{
  const int bid = blockIdx.x;
  const int xcd = bid & 7;
  const int j   = bid >> 3;                       // 0..31
  const int m0  = ((xcd << 2) + (j >> 3)) * 128;
  const int n0  = (j & 7) * 128;
  gemm_async<true>(A, cWo, bias, C, DD, DD, m0, n0, 1.0f);
}

// ---------------------------------------------------------------------------
// FALLBACK GEMM core (round-7 verified): explicit staging, padded LDS.
// ---------------------------------------------------------------------------
template<bool A_BF16, bool W_BF16, bool OUT_F32>
__device__ __forceinline__ void gemm_core(
    const void* __restrict__ A, const void* __restrict__ W,
    const float* __restrict__ bias, void* __restrict__ Cv,
    const int K, const int N, const int m0, const int n0, const float scale)
{
  __shared__ __align__(16) u16 sA[128*GSTRIDE];
  __shared__ __align__(16) u16 sB[128*GSTRIDE];

  const int tid  = threadIdx.x;
  const int wave = tid >> 6;
  const int lane = tid & 63;
  const int quad = lane >> 4;
  const int lr   = lane & 15;
  const int wm   = wave >> 1;
  const int wn   = wave & 1;
  const int srow = tid >> 1;
  const int scol = (tid & 1) * 16;

  floatx4 acc[4][4];
#pragma unroll
  for (int i = 0; i < 4; ++i)
#pragma unroll
    for (int j = 0; j < 4; ++j) acc[i][j] = (floatx4){0.f, 0.f, 0.f, 0.f};

  const size_t offA = (size_t)(m0 + srow) * K + scol;
  const size_t offW = (size_t)(n0 + srow) * K + scol;

  const int nk = K >> 5;
  for (int kt = 0; kt < nk; ++kt) {
    const int k0 = kt << 5;
    short8 a0, a1, b0, b1;
    if (A_BF16) {
      const u16* p = (const u16*)A + offA + k0;
      a0 = *(const short8*)p; a1 = *(const short8*)(p + 8);
    } else {
      pack16((const float4*)((const float*)A + offA + k0), a0, a1);
    }
    if (W_BF16) {
      const u16* p = (const u16*)W + offW + k0;
      b0 = *(const short8*)p; b1 = *(const short8*)(p + 8);
    } else {
      pack16((const float4*)((const float*)W + offW + k0), b0, b1);
    }
    __syncthreads();
    *(short8*)(sA + srow * GSTRIDE + scol)     = a0;
    *(short8*)(sA + srow * GSTRIDE + scol + 8) = a1;
    *(short8*)(sB + srow * GSTRIDE + scol)     = b0;
    *(short8*)(sB + srow * GSTRIDE + scol + 8) = b1;
    __syncthreads();

    short8 af[4], bf[4];
#pragma unroll
    for (int t = 0; t < 4; ++t) {
      af[t] = *(const short8*)(sA + (wm*64 + t*16 + lr)*GSTRIDE + quad*8);
      bf[t] = *(const short8*)(sB + (wn*64 + t*16 + lr)*GSTRIDE + quad*8);
    }
#pragma unroll
    for (int i = 0; i < 4; ++i)
#pragma unroll
      for (int j = 0; j < 4; ++j)
        acc[i][j] = __builtin_amdgcn_mfma_f32_16x16x32_bf16(af[i], bf[j], acc[i][j], 0, 0, 0);
  }

#pragma unroll
  for (int i = 0; i < 4; ++i) {
    const int mb = m0 + wm*64 + i*16 + quad*4;
#pragma unroll
    for (int j = 0; j < 4; ++j) {
      const int n = n0 + wn*64 + j*16 + lr;
      const float bsv = bias[n];
#pragma unroll
      for (int r = 0; r < 4; ++r) {
        const size_t idx = (size_t)(mb + r) * N + n;
        const float v = (acc[i][j][r] + bsv) * scale;
        if (OUT_F32) ((float*)Cv)[idx] = v;
        else         ((u16*)Cv)[idx]   = f2b(v);
      }
    }
  }
}

__global__ __launch_bounds__(256, 2) void gemm_qkv_fb(
    const float* __restrict__ Qin, const float* __restrict__ Kin, const float* __restrict__ Vin,
    const u16* __restrict__ cWq, const u16* __restrict__ cWk, const u16* __restrict__ cWv,
    const float* __restrict__ bq, const float* __restrict__ bk, const float* __restrict__ bv,
    u16* __restrict__ oQ, u16* __restrict__ oK, u16* __restrict__ oV)
{
  const int wsel = blockIdx.x >> 3;
  const int n0 = (blockIdx.x & 7) * 128;
  const int m0 = blockIdx.y * 128;
  const float* A; const u16* W; const float* bias; u16* C;
  if (wsel == 0)      { A = Qin; W = cWq; bias = bq; C = oQ; }
  else if (wsel == 1) { A = Kin; W = cWk; bias = bk; C = oK; }
  else                { A = Vin; W = cWv; bias = bv; C = oV; }
  const float scale = (wsel == 0) ? QSCALE : 1.0f;
  gemm_core<false, true, false>(A, W, bias, C, DD, DD, m0, n0, scale);
}
__global__ __launch_bounds__(256, 2) void gemm_out_fb(
    const u16* __restrict__ A, const float* __restrict__ W,
    const float* __restrict__ bias, float* __restrict__ C)
{
  gemm_core<true, false, true>((const void*)A, (const void*)W, bias, C, DD, DD,
                               blockIdx.y * 128, blockIdx.x * 128, 1.0f);
}

// ---------------------------------------------------------------------------
// V transpose: pV[B,S,D] (head h cols) -> Vt[B,H,dk,S]
// ---------------------------------------------------------------------------
__global__ __launch_bounds__(256) void transpose_v(
    const u16* __restrict__ Vp, u16* __restrict__ Vt)
{
  __shared__ u16 t[64 * 65];
  const int st = blockIdx.x, h = blockIdx.y, b = blockIdx.z;

  const int r  = threadIdx.x >> 2;
  const int c0 = (threadIdx.x & 3) * 16;
  const u16* src = Vp + ((size_t)(b * SS + st * 64 + r)) * DD + h * 64 + c0;
  short8 v0 = *(const short8*)src;
  short8 v1 = *(const short8*)(src + 8);
#pragma unroll
  for (int i = 0; i < 8; ++i) {
    t[r * 65 + c0 + i]     = (u16)v0[i];
    t[r * 65 + c0 + 8 + i] = (u16)v1[i];
  }
  __syncthreads();
  union { u16 a[16]; short8 v[2]; } ob;
#pragma unroll
  for (int i = 0; i < 16; ++i) ob.a[i] = t[(c0 + i) * 65 + r];
  u16* dst = Vt + (((size_t)(b * HH + h)) * DKK + r) * SS + st * 64 + c0;
  *(short8*)dst       = ob.v[0];
  *(short8*)(dst + 8) = ob.v[1];
}

// ---------------------------------------------------------------------------
// Flash attention, q-tile 128: block = 256 threads = 4 waves; each wave owns
// TWO groups of 16 q-cols (32 q), sharing the K and V fragments across groups.
//
// R7 = R6 with the compile fix: __exp2f -> __builtin_amdgcn_exp2f (v_exp_f32).
//  * exp2-direct: Q pre-scaled by log2e/sqrt(dk) -> p = exp2(st-mn).
//  * v_cvt_pk_bf16_f32 packed RNE bf16 conversion (16 ops vs ~128).
//  * l-sum cross-quad shfl reduction deferred to epilogue.
// Keeps: reg-Q, shared K/V frags, XOR-swizzled LDS, 1-barrier dbuf pipeline,
// XCD swizzle, setprio, defer-rescale (threshold 11.54 = 8*log2e).
// ---------------------------------------------------------------------------
__device__ __forceinline__ int aswz(int row, int cb) {   // byte offset in 128B-row tile
  return (row << 7) + (cb ^ ((row & 7) << 4));
}

__global__ __launch_bounds__(256, 2) void attn(
    const u16* __restrict__ Qp, const u16* __restrict__ Kp,
    const u16* __restrict__ Vt, u16* __restrict__ O)
{
  __shared__ __align__(16) char sK[2][64 * 128];
  __shared__ __align__(16) char sV[2][64 * 128];
  __shared__ __align__(16) char sP[4][32 * 128];

  const int tid = threadIdx.x, wave = tid >> 6, lane = tid & 63;
  const int quad = lane >> 4, lr = lane & 15;

  // XCD-aware bijective swizzle over 512 blocks (512%8==0)
  const int flat = (blockIdx.z * 16 + blockIdx.y) * 16 + blockIdx.x;
  const int swzb = (flat & 7) * 64 + (flat >> 3);
  const int qb = swzb & 15;
  const int h  = (swzb >> 4) & 15;
  const int b  = swzb >> 8;
  const size_t vbase = ((size_t)(b * HH + h)) * DKK * SS;

  // Q fragments in registers: [group][k-half], loop-invariant
  short8 qf[2][2];
#pragma unroll
  for (int g = 0; g < 2; ++g) {
    const u16* qr = Qp + ((size_t)(b * SS + qb * 128 + wave * 32 + g * 16 + lr)) * DD + h * 64 + quad * 8;
    qf[g][0] = *(const short8*)qr;
    qf[g][1] = *(const short8*)(qr + 32);
  }

  floatx4 accO[2][4];
  float m_l[2] = { -3e38f, -3e38f }, l_l[2] = { 0.f, 0.f };
#pragma unroll
  for (int g = 0; g < 2; ++g)
#pragma unroll
    for (int t = 0; t < 4; ++t) accO[g][t] = (floatx4){0.f, 0.f, 0.f, 0.f};

  // staging: 256 threads, each 32B (two short8) of K and of V per tile
  const int sr = tid >> 2;            // 0..63 (row)
  const int ce = (tid & 3) * 16;      // elem col 0..48
  const u16* kp = Kp + ((size_t)(b * SS + sr)) * DD + h * 64 + ce;
  const u16* vp = Vt + vbase + (size_t)sr * SS + ce;
  const int dk0 = aswz(sr, ce * 2), dk1 = aswz(sr, ce * 2 + 16);

  // prologue: tile0 -> LDS buf0; tile1 -> regs; one barrier
  short8 rk0 = *(const short8*)kp,        rk1 = *(const short8*)(kp + 8);
  short8 rv0 = *(const short8*)vp,        rv1 = *(const short8*)(vp + 8);
  *(short8*)(sK[0] + dk0) = rk0;  *(short8*)(sK[0] + dk1) = rk1;
  *(short8*)(sV[0] + dk0) = rv0;  *(short8*)(sV[0] + dk1) = rv1;
  kp += (size_t)64 * DD; vp += 64;
  rk0 = *(const short8*)kp;  rk1 = *(const short8*)(kp + 8);
  rv0 = *(const short8*)vp;  rv1 = *(const short8*)(vp + 8);
  __syncthreads();

  const int nt = SS / 64;
  for (int kt = 0; kt < nt; ++kt) {
    const int cur = kt & 1;
    // write tile kt+1 (loaded one iteration ago) into the other buffer
    if (kt < nt - 1) {
      *(short8*)(sK[cur ^ 1] + dk0) = rk0;  *(short8*)(sK[cur ^ 1] + dk1) = rk1;
      *(short8*)(sV[cur ^ 1] + dk0) = rv0;  *(short8*)(sV[cur ^ 1] + dk1) = rv1;
    }
    // issue global loads for tile kt+2 (consumed next iteration)
    if (kt < nt - 2) {
      kp += (size_t)64 * DD; vp += 64;
      rk0 = *(const short8*)kp;  rk1 = *(const short8*)(kp + 8);
      rv0 = *(const short8*)vp;  rv1 = *(const short8*)(vp + 8);
    }
    const char* sKc = sK[cur];
    const char* sVc = sV[cur];
    char* sPw = sP[wave];

    // K and V fragments: loaded ONCE, shared by both q-groups
    short8 kf[4][2], vf[4][2];
#pragma unroll
    for (int t = 0; t < 4; ++t) {
      const int row = t * 16 + lr;
      kf[t][0] = *(const short8*)(sKc + aswz(row, quad * 16));
      kf[t][1] = *(const short8*)(sKc + aswz(row, 64 + quad * 16));
      vf[t][0] = *(const short8*)(sVc + aswz(row, quad * 16));
      vf[t][1] = *(const short8*)(sVc + aswz(row, 64 + quad * 16));
    }

#pragma unroll
    for (int g = 0; g < 2; ++g) {
      // S^T[k][q] for this group's 16 q-cols: A = K rows, B = Q rows
      floatx4 st[4];
      __builtin_amdgcn_s_setprio(1);
#pragma unroll
      for (int t = 0; t < 4; ++t) {
        floatx4 cc = (floatx4){0.f, 0.f, 0.f, 0.f};
        cc = __builtin_amdgcn_mfma_f32_16x16x32_bf16(kf[t][0], qf[g][0], cc, 0, 0, 0);
        cc = __builtin_amdgcn_mfma_f32_16x16x32_bf16(kf[t][1], qf[g][1], cc, 0, 0, 0);
        st[t] = cc;
      }
      __builtin_amdgcn_s_setprio(0);

      float mx = st[0][0];
#pragma unroll
      for (int t = 0; t < 4; ++t)
#pragma unroll
        for (int r = 0; r < 4; ++r) mx = fmaxf(mx, st[t][r]);
      mx = fmaxf(mx, __shfl_xor(mx, 16, 64));
      mx = fmaxf(mx, __shfl_xor(mx, 32, 64));

      // defer-rescale (T13): only rescale when the max grew by > 8*log2e
      if (!__all(mx - m_l[g] <= 11.54f)) {
        const float mn2 = fmaxf(m_l[g], mx);
        const float al = ex2(m_l[g] - mn2);
        m_l[g] = mn2;
        l_l[g] *= al;
        float arow[4];
#pragma unroll
        for (int r = 0; r < 4; ++r) arow[r] = __shfl(al, quad * 4 + r, 64);
#pragma unroll
        for (int t = 0; t < 4; ++t) {
          floatx4 o = accO[g][t];
          o[0] *= arow[0]; o[1] *= arow[1]; o[2] *= arow[2]; o[3] *= arow[3];
          accO[g][t] = o;
        }
      }
      const float mn = m_l[g];

      float rs = 0.f;
      u16x4 pk[4];
#pragma unroll
      for (int t = 0; t < 4; ++t) {
        const float p0 = ex2(st[t][0] - mn);
        const float p1 = ex2(st[t][1] - mn);
        const float p2 = ex2(st[t][2] - mn);
        const float p3 = ex2(st[t][3] - mn);
        rs += (p0 + p1) + (p2 + p3);
        union { unsigned u[2]; u16x4 v; } pp;
        pp.u[0] = cvt_pk_bf16(p0, p1);
        pp.u[1] = cvt_pk_bf16(p2, p3);
        pk[t] = pp.v;
      }
      l_l[g] += rs;   // per-lane partial; cross-quad reduce deferred to epilogue

#pragma unroll
      for (int t = 0; t < 4; ++t)
        *(u16x4*)(sPw + aswz(g * 16 + lr, t * 32 + quad * 8)) = pk[t];
      // no barrier: sP is per-wave; within-wave LDS write->read ordered by lgkmcnt

      // O += P @ V
      short8 p0 = *(const short8*)(sPw + aswz(g * 16 + lr, quad * 16));
      short8 p1 = *(const short8*)(sPw + aswz(g * 16 + lr, 64 + quad * 16));
      __builtin_amdgcn_s_setprio(1);
#pragma unroll
      for (int t = 0; t < 4; ++t) {
        accO[g][t] = __builtin_amdgcn_mfma_f32_16x16x32_bf16(p0, vf[t][0], accO[g][t], 0, 0, 0);
        accO[g][t] = __builtin_amdgcn_mfma_f32_16x16x32_bf16(p1, vf[t][1], accO[g][t], 0, 0, 0);
      }
      __builtin_amdgcn_s_setprio(0);
    }

    __syncthreads();   // single barrier: next-tile writes visible; this-tile reads done
  }

#pragma unroll
  for (int g = 0; g < 2; ++g) {
    // finish the deferred denominator reduction across quads
    l_l[g] += __shfl_xor(l_l[g], 16, 64);
    l_l[g] += __shfl_xor(l_l[g], 32, 64);
    float lrow[4];
#pragma unroll
    for (int r = 0; r < 4; ++r) lrow[r] = __shfl(l_l[g], quad * 4 + r, 64);
#pragma unroll
    for (int t = 0; t < 4; ++t)
#pragma unroll
      for (int r = 0; r < 4; ++r) {
        const int s = qb * 128 + wave * 32 + g * 16 + quad * 4 + r;
        const int d = h * 64 + t * 16 + lr;
        O[((size_t)(b * SS + s)) * DD + d] = f2b(accO[g][t][r] / lrow[r]);
      }
  }
}

// ---------------------------------------------------------------------------
extern "C" void kernel_launch(void* const* d_in, const int* in_sizes, int n_in,
                              void* d_out, int out_size, void* d_ws, size_t ws_size,
                              hipStream_t stream)
{
  const float* Qin = (const float*)d_in[0];
  const float* Kin = (const float*)d_in[1];
  const float* Vin = (const float*)d_in[2];
  const float* Wq  = (const float*)d_in[3];
  const float* bq  = (const float*)d_in[4];
  const float* Wk  = (const float*)d_in[5];
  const float* bk  = (const float*)d_in[6];
  const float* Wv  = (const float*)d_in[7];
  const float* bv  = (const float*)d_in[8];
  const float* Wo  = (const float*)d_in[9];
  const float* bo  = (const float*)d_in[10];
  float* out = (float*)d_out;

  const size_t TSZ = (size_t)MT * DD;   // 4M elements
  const size_t WSZ = (size_t)DD * DD;   // 1M elements
  dim3 blk(256);

  // d_out scratch for Wq/Wk/Wv bf16 (consumed by gemm_qkv; overwritten at end)
  u16* cWq = (u16*)d_out;
  u16* cWk = cWq + WSZ;
  u16* cWv = cWk + WSZ;

  u16* pQ   = (u16*)d_ws;
  u16* pK   = pQ  + TSZ;
  u16* pV   = pK  + TSZ;
  u16* wsVt = pV  + TSZ;
  u16* wsO  = wsVt + TSZ;

  if (ws_size >= (8*TSZ + WSZ) * sizeof(u16)) {
    u16* cQ  = wsO + TSZ;
    u16* cK  = cQ  + TSZ;
    u16* cV  = cK  + TSZ;
    u16* cWo = cV  + TSZ;
    cast_all<<<dim3(TSZ/8/256, 7), blk, 0, stream>>>(
        Qin, Kin, Vin, Wq, Wk, Wv, Wo, cQ, cK, cV, cWq, cWk, cWv, cWo);
    gemm_qkv_async<<<dim3(768), blk, 0, stream>>>(
        cQ, cK, cV, cWq, cWk, cWv, bq, bk, bv, pQ, pK, pV);
    transpose_v<<<dim3(SS/64, HH, BB), blk, 0, stream>>>(pV, wsVt);
    attn<<<dim3(SS/128, HH, BB), blk, 0, stream>>>(pQ, pK, wsVt, wsO);
    gemm_out_async<<<dim3(256), blk, 0, stream>>>(wsO, cWo, bo, out);
  } else {
    cast_w3<<<dim3(WSZ/8/256, 3), blk, 0, stream>>>(Wq, Wk, Wv, cWq);
    gemm_qkv_fb<<<dim3(24, MT/128), blk, 0, stream>>>(
        Qin, Kin, Vin, cWq, cWk, cWv, bq, bk, bv, pQ, pK, pV);
    transpose_v<<<dim3(SS/64, HH, BB), blk, 0, stream>>>(pV, wsVt);
    attn<<<dim3(SS/128, HH, BB), blk, 0, stream>>>(pQ, pK, wsVt, wsO);
    gemm_out_fb<<<dim3(DD/128, MT/128), blk, 0, stream>>>(wsO, Wo, bo, out);
  }
}